// Round 10
// baseline (372.568 us; speedup 1.0000x reference)
//
#include <hip/hip_runtime.h>
#include <hip/hip_bf16.h>
#include <math.h>

typedef __bf16 bf16x8 __attribute__((ext_vector_type(8)));
typedef float f32x4 __attribute__((ext_vector_type(4)));

#define SEQ 1500
#define CDIM 1280
#define NHEAD 20
#define DHEAD 64
#define NMLP 5120
#define QKVN 3840
#define VTLD 1504   // leading dim of transposed V (47*32)
#define APAD 68     // attention LDS stride

#define GLOAD_LDS16(gp, lp)                                                    \
  __builtin_amdgcn_global_load_lds(                                            \
      (const __attribute__((address_space(1))) unsigned int*)(gp),             \
      (__attribute__((address_space(3))) unsigned int*)(lp), 16, 0, 0)

// ---------------- per-block input-dtype detect (1KB ballot vote on x) ------
__device__ __forceinline__ int detect_bf(const unsigned int* __restrict__ xw,
                                         int tid) {
  __shared__ int shdet[4];
  const unsigned int w = xw[tid & 255];
  const unsigned int e = (w >> 7) & 0xFF;
  const unsigned long long b = __ballot(e >= 100 && e <= 150);
  if ((tid & 63) == 0) shdet[tid >> 6] = (int)__popcll(b);
  __syncthreads();
  return (shdet[0] + shdet[1] + shdet[2] + shdet[3]) >= 160;
}

// ---------------- fused prologue: pack + all weight transposes + LN1 -------
// R9: merges 3 launches into 1. Each block self-detects dtype (no flag dep).
// pb layout: [0,3840) qkvbias (bq|0|bv) | 3840 bo | 5120 g1 | 6400 be1 |
//            7680 g2 | 8960 be2 | 10240 b1(5120) | 15360 b2
__device__ __forceinline__ void transpose_body(const void* in, __bf16* out,
                                               int K, int N, int isbf,
                                               int bx, int by, int tid) {
  __shared__ __bf16 t[32][33];
  const int tx = tid & 31, ty = tid >> 5;
  const int n0 = bx * 32, k0 = by * 32;
  if (isbf) {
    const __bf16* s = (const __bf16*)in;
#pragma unroll
    for (int i = ty; i < 32; i += 8)
      t[i][tx] = s[(size_t)(k0 + i) * N + n0 + tx];
  } else {
    const float* s = (const float*)in;
#pragma unroll
    for (int i = ty; i < 32; i += 8)
      t[i][tx] = (__bf16)s[(size_t)(k0 + i) * N + n0 + tx];
  }
  __syncthreads();
#pragma unroll
  for (int i = ty; i < 32; i += 8)
    out[(size_t)(n0 + i) * K + k0 + tx] = t[tx][i];
}

__global__ __launch_bounds__(256) void prep_kernel(
    const unsigned int* __restrict__ xw, const void* __restrict__ X,
    const void* bq, const void* bv, const void* bo,
    const void* g1, const void* be1, const void* g2, const void* be2,
    const void* b1, const void* b2,
    const void* Wq, const void* Wk, const void* Wv, const void* Wo,
    const void* W1, const void* W2,
    __bf16* __restrict__ pb, int* __restrict__ flag,
    __bf16* __restrict__ Wqkvt, __bf16* __restrict__ Wot,
    __bf16* __restrict__ W1t, __bf16* __restrict__ W2t,
    __bf16* __restrict__ Y) {
  const int tid = threadIdx.x;
  const int isbf = detect_bf(xw, tid);
  auto ld = [&](const void* p, int j) -> float {
    return isbf ? (float)((const __bf16*)p)[j] : ((const float*)p)[j];
  };
  const int id = blockIdx.x;

  if (id < 65) {
    // ---- pack params ----
    if (id == 0 && tid == 0) flag[0] = isbf;
    const int i = id * 256 + tid;
    if (i >= 16640) return;
    float v;
    if (i < 3840) {
      if (i < 1280) v = ld(bq, i);
      else if (i < 2560) v = 0.f;
      else v = ld(bv, i - 2560);
    } else if (i < 5120) v = ld(bo, i - 3840);
    else if (i < 6400) v = ld(g1, i - 5120);
    else if (i < 7680) v = ld(be1, i - 6400);
    else if (i < 8960) v = ld(g2, i - 7680);
    else if (i < 10240) v = ld(be2, i - 8960);
    else if (i < 15360) v = ld(b1, i - 10240);
    else v = ld(b2, i - 15360);
    pb[i] = (__bf16)v;
  } else if (id < 65 + 19200) {
    // ---- weight transposes ----
    const int wid = id - 65;
    if (wid < 6400) {                     // Wq|Wk|Wv|Wo : 4 x (40x40)
      const int w = wid / 1600, r = wid % 1600;
      const void* in = (w == 0) ? Wq : (w == 1) ? Wk : (w == 2) ? Wv : Wo;
      __bf16* out = (w < 3) ? (Wqkvt + (size_t)w * CDIM * CDIM) : Wot;
      transpose_body(in, out, CDIM, CDIM, isbf, r % 40, r / 40, tid);
    } else if (wid < 12800) {             // W1 : 160x40
      const int r = wid - 6400;
      transpose_body(W1, W1t, CDIM, NMLP, isbf, r % 160, r / 160, tid);
    } else {                              // W2 : 40x160
      const int r = wid - 12800;
      transpose_body(W2, W2t, NMLP, CDIM, isbf, r % 40, r / 40, tid);
    }
  } else {
    // ---- LN1 ----
    const int row = id - (65 + 19200);
    const int isf32 = !isbf;
    float v[5];
    float s = 0.f, s2 = 0.f;
#pragma unroll
    for (int i = 0; i < 5; ++i) {
      const int c = tid + 256 * i;
      const size_t idx = (size_t)row * CDIM + c;
      v[i] = isf32 ? ((const float*)X)[idx] : (float)((const __bf16*)X)[idx];
      s += v[i];
      s2 += v[i] * v[i];
    }
    const int lane = tid & 63, wv = tid >> 6;
#pragma unroll
    for (int off = 32; off > 0; off >>= 1) {
      s += __shfl_down(s, off);
      s2 += __shfl_down(s2, off);
    }
    __shared__ float red[8];
    if (lane == 0) { red[wv] = s; red[4 + wv] = s2; }
    __syncthreads();
    s = red[0] + red[1] + red[2] + red[3];
    s2 = red[4] + red[5] + red[6] + red[7];
    const float mu = s * (1.f / CDIM);
    const float var = s2 * (1.f / CDIM) - mu * mu;
    const float rstd = rsqrtf(fmaxf(var, 0.f) + 1e-5f);
#pragma unroll
    for (int i = 0; i < 5; ++i) {
      const int c = tid + 256 * i;
      Y[(size_t)row * CDIM + c] =
          (__bf16)((v[i] - mu) * rstd * ld(g1, c) + ld(be1, c));
    }
  }
}

// ---------------- activation transpose: [SEQ][.] -> [N][VTLD] --------------
__global__ __launch_bounds__(256) void transpose_act_kernel(const __bf16* __restrict__ in,
                                                            __bf16* __restrict__ out,
                                                            int istride) {
  __shared__ __bf16 t[32][33];
  const int tx = threadIdx.x, ty = threadIdx.y;
  const int n0 = blockIdx.x * 32, k0 = blockIdx.y * 32;
#pragma unroll
  for (int i = ty; i < 32; i += 8) {
    const int k = k0 + i;
    t[i][tx] = (k < SEQ) ? in[(size_t)k * istride + n0 + tx] : (__bf16)0.f;
  }
  __syncthreads();
#pragma unroll
  for (int i = ty; i < 32; i += 8) {
    const int kk = k0 + tx;
    if (kk < VTLD) out[(size_t)(n0 + i) * VTLD + kk] = t[tx][i];
  }
}

// ---------------- fused: x1 = x + sum(P) + bo ; h2 = LN2(x1) ----------------
__global__ __launch_bounds__(256) void resid_ln_kernel(
    const float* __restrict__ P, const __bf16* __restrict__ bo,
    const void* __restrict__ X, const __bf16* __restrict__ gamma,
    const __bf16* __restrict__ beta, __bf16* __restrict__ X1,
    __bf16* __restrict__ H2, const int* __restrict__ flag) {
  const int isf32 = (flag[0] == 0);
  const int row = blockIdx.x;
  const int MN = SEQ * CDIM;
  float v[5];
  float s = 0.f, s2 = 0.f;
#pragma unroll
  for (int i = 0; i < 5; ++i) {
    const int c = threadIdx.x + 256 * i;
    const size_t idx = (size_t)row * CDIM + c;
    const float xv = isf32 ? ((const float*)X)[idx] : (float)((const __bf16*)X)[idx];
    const float val = P[idx] + P[MN + idx] + (float)bo[c] + xv;
    X1[idx] = (__bf16)val;
    v[i] = val;
    s += val;
    s2 += val * val;
  }
  const int lane = threadIdx.x & 63, wv = threadIdx.x >> 6;
#pragma unroll
  for (int off = 32; off > 0; off >>= 1) {
    s += __shfl_down(s, off);
    s2 += __shfl_down(s2, off);
  }
  __shared__ float red[8];
  if (lane == 0) { red[wv] = s; red[4 + wv] = s2; }
  __syncthreads();
  s = red[0] + red[1] + red[2] + red[3];
  s2 = red[4] + red[5] + red[6] + red[7];
  const float mu = s * (1.f / CDIM);
  const float var = s2 * (1.f / CDIM) - mu * mu;
  const float rstd = rsqrtf(fmaxf(var, 0.f) + 1e-5f);
#pragma unroll
  for (int i = 0; i < 5; ++i) {
    const int c = threadIdx.x + 256 * i;
    H2[(size_t)row * CDIM + c] =
        (__bf16)((v[i] - mu) * rstd * (float)gamma[c] + (float)beta[c]);
  }
}

// ---------------- GEMM 64x128 tile, BK=64 (2 x 32 chunks), 2-barrier -------
// (R5 structure, proven). nsplit>1: fp32 partials. Used for Wo / MLP2.
__global__ __launch_bounds__(256) void gemm64_kernel(
    const __bf16* __restrict__ A, const __bf16* __restrict__ Bt,
    const __bf16* __restrict__ bias, void* __restrict__ Cv,
    int M, int N, int K, int KS, int gelu, int nsplit) {
  __shared__ __bf16 As[2][64 * 32];
  __shared__ __bf16 Bs[2][128 * 32];
  const int bm = blockIdx.x, bn = blockIdx.y, sz = blockIdx.z;
  const int tid = threadIdx.x;
  const int lane = tid & 63, wave = tid >> 6;
  const int l16 = lane & 15, kq = (lane >> 4) << 3;
  const int lrow = lane >> 2, lcol = (lane & 3) << 3;
  const int wn = wave * 32;

  f32x4 acc[4][2];
  const f32x4 zero = {0.f, 0.f, 0.f, 0.f};
#pragma unroll
  for (int i = 0; i < 4; ++i)
#pragma unroll
    for (int j = 0; j < 2; ++j) acc[i][j] = zero;

  const int kbeg = sz * KS;
  int kend = kbeg + KS;
  if (kend > K) kend = K;

  int ga = bm * 64 + wave * 16 + lrow;
  if (ga > M - 1) ga = M - 1;  // clamp: garbage rows never stored
  const __bf16* Ap = A + (size_t)ga * K + lcol;

  for (int k0 = kbeg; k0 < kend; k0 += 64) {
#pragma unroll
    for (int c = 0; c < 2; ++c)
      GLOAD_LDS16(Ap + k0 + c * 32, &As[c][wave * 512]);
#pragma unroll
    for (int c = 0; c < 2; ++c)
#pragma unroll
      for (int t = 0; t < 2; ++t) {
        const int seg = t * 4 + wave;
        const int gb = bn * 128 + seg * 16 + lrow;  // N multiple of 128
        GLOAD_LDS16(Bt + (size_t)gb * K + k0 + c * 32 + lcol, &Bs[c][seg * 512]);
      }
    __syncthreads();
    bf16x8 af[4][2], bfr[2][2];
#pragma unroll
    for (int i = 0; i < 4; ++i)
#pragma unroll
      for (int c = 0; c < 2; ++c)
        af[i][c] = *(const bf16x8*)(&As[c][(i * 16 + l16) * 32 + kq]);
#pragma unroll
    for (int j = 0; j < 2; ++j)
#pragma unroll
      for (int c = 0; c < 2; ++c)
        bfr[j][c] = *(const bf16x8*)(&Bs[c][(wn + j * 16 + l16) * 32 + kq]);
#pragma unroll
    for (int i = 0; i < 4; ++i)
#pragma unroll
      for (int j = 0; j < 2; ++j)
#pragma unroll
        for (int c = 0; c < 2; ++c)
          acc[i][j] = __builtin_amdgcn_mfma_f32_16x16x32_bf16(af[i][c], bfr[j][c],
                                                              acc[i][j], 0, 0, 0);
    __syncthreads();
  }

  const int rq4 = (lane >> 4) * 4;
  if (nsplit > 1) {
    float* P = (float*)Cv + (size_t)sz * M * N;
#pragma unroll
    for (int i = 0; i < 4; ++i)
#pragma unroll
      for (int r = 0; r < 4; ++r) {
        const int grow = bm * 64 + i * 16 + rq4 + r;
        if (grow >= M) continue;
#pragma unroll
        for (int j = 0; j < 2; ++j) {
          const int gcol = bn * 128 + wn + j * 16 + l16;
          P[(size_t)grow * N + gcol] = acc[i][j][r];
        }
      }
  } else {
    __bf16* Cb = (__bf16*)Cv;
#pragma unroll
    for (int i = 0; i < 4; ++i)
#pragma unroll
      for (int r = 0; r < 4; ++r) {
        const int grow = bm * 64 + i * 16 + rq4 + r;
        if (grow >= M) continue;
#pragma unroll
        for (int j = 0; j < 2; ++j) {
          const int gcol = bn * 128 + wn + j * 16 + l16;
          float vv = acc[i][j][r];
          if (bias) vv += (float)bias[gcol];
          if (gelu) vv = 0.5f * vv * (1.f + erff(vv * 0.70710678118654752f));
          Cb[(size_t)grow * N + gcol] = (__bf16)vv;
        }
      }
  }
}

// ---------------- GEMM 128x128, BK=64, counted-vmcnt dbuf (R5 win) ---------
__global__ __launch_bounds__(256, 2) void gemm128c_kernel(
    const __bf16* __restrict__ A, const __bf16* __restrict__ Bt,
    const __bf16* __restrict__ bias, __bf16* __restrict__ C,
    int M, int N, int K, int gelu, int mtiles) {
  __shared__ __bf16 As[2][128 * 64];   // 16 KiB per buf
  __shared__ __bf16 Bs[2][128 * 64];

  // bijective XCD swizzle (m204)
  const int nwg = mtiles * (N >> 7);
  const int qq = nwg >> 3, rr = nwg & 7;
  const int xcd = blockIdx.x & 7, rk = blockIdx.x >> 3;
  const int wg = (xcd < rr ? xcd * (qq + 1) : rr * (qq + 1) + (xcd - rr) * qq) + rk;
  const int bm = wg % mtiles, bn = wg / mtiles;

  const int tid = threadIdx.x;
  const int lane = tid & 63, wave = tid >> 6;
  const int wm = (wave >> 1) * 64, wn = (wave & 1) * 64;   // 2x2 wave grid
  const int l16 = lane & 15, quad = lane >> 4;

  const int rT = tid >> 3, sl = tid & 7;
  const int aoff = ((sl * 16) ^ ((rT & 7) << 4)) >> 1;     // elems
  const __bf16* Ap[4];
  const __bf16* Bp[4];
#pragma unroll
  for (int s = 0; s < 4; ++s) {
    int gm = bm * 128 + s * 32 + rT;
    if (gm > M - 1) gm = M - 1;      // clamp: garbage rows never stored
    Ap[s] = A + (size_t)gm * K + aoff;
    Bp[s] = Bt + (size_t)(bn * 128 + s * 32 + rT) * K + aoff;
  }
  const int ldst = tid * 8;

  const int xsw = (l16 & 7) << 4;
  const int kb0 = ((quad << 4) ^ xsw) >> 1;
  const int kb1 = (((quad << 4) + 64) ^ xsw) >> 1;

  f32x4 acc[4][4];
  const f32x4 zero = {0.f, 0.f, 0.f, 0.f};
#pragma unroll
  for (int i = 0; i < 4; ++i)
#pragma unroll
    for (int j = 0; j < 4; ++j) acc[i][j] = zero;

  const int NT = K >> 6;

#define STAGE128(b, k0)                                       \
  do {                                                        \
    _Pragma("unroll")                                         \
    for (int s = 0; s < 4; ++s) {                             \
      GLOAD_LDS16(Ap[s] + (k0), &As[b][s * 2048 + ldst]);     \
      GLOAD_LDS16(Bp[s] + (k0), &Bs[b][s * 2048 + ldst]);     \
    }                                                         \
  } while (0)

  STAGE128(0, 0);
  for (int t = 0; t < NT; ++t) {
    const int cur = t & 1;
    if (t + 1 < NT) {
      STAGE128(cur ^ 1, (t + 1) * 64);
      asm volatile("s_waitcnt vmcnt(8)" ::: "memory");
    } else {
      asm volatile("s_waitcnt vmcnt(0)" ::: "memory");
    }
    __builtin_amdgcn_s_barrier();
    __builtin_amdgcn_sched_barrier(0);
    bf16x8 af[4][2], bfr[4][2];
#pragma unroll
    for (int i = 0; i < 4; ++i) {
      const int row = (wm + i * 16 + l16) * 64;
      af[i][0] = *(const bf16x8*)(&As[cur][row + kb0]);
      af[i][1] = *(const bf16x8*)(&As[cur][row + kb1]);
    }
#pragma unroll
    for (int j = 0; j < 4; ++j) {
      const int row = (wn + j * 16 + l16) * 64;
      bfr[j][0] = *(const bf16x8*)(&Bs[cur][row + kb0]);
      bfr[j][1] = *(const bf16x8*)(&Bs[cur][row + kb1]);
    }
    __builtin_amdgcn_s_setprio(1);
#pragma unroll
    for (int i = 0; i < 4; ++i)
#pragma unroll
      for (int j = 0; j < 4; ++j)
#pragma unroll
        for (int c = 0; c < 2; ++c)
          acc[i][j] = __builtin_amdgcn_mfma_f32_16x16x32_bf16(af[i][c], bfr[j][c],
                                                              acc[i][j], 0, 0, 0);
    __builtin_amdgcn_s_setprio(0);
    __builtin_amdgcn_s_barrier();
    __builtin_amdgcn_sched_barrier(0);
  }
#undef STAGE128

#pragma unroll
  for (int i = 0; i < 4; ++i)
#pragma unroll
    for (int r = 0; r < 4; ++r) {
      const int grow = bm * 128 + wm + i * 16 + quad * 4 + r;
      if (grow >= M) continue;
#pragma unroll
      for (int j = 0; j < 4; ++j) {
        const int gcol = bn * 128 + wn + j * 16 + l16;
        float vv = acc[i][j][r];
        if (bias) vv += (float)bias[gcol];
        if (gelu) vv = 0.5f * vv * (1.f + erff(vv * 0.70710678118654752f));
        C[(size_t)grow * N + gcol] = (__bf16)vv;
      }
    }
}

// ---------------- final reduce: out = resid + sum(P) + bias ----------------
__global__ __launch_bounds__(256) void reduce_kernel(
    const float* __restrict__ P, const __bf16* __restrict__ bias,
    const __bf16* __restrict__ resid, void* __restrict__ out,
    int MN, int N, const int* __restrict__ flag) {
  const int i = blockIdx.x * 256 + threadIdx.x;
  if (i >= MN) return;
  const float v = P[i] + P[(size_t)MN + i] + (float)bias[i % N] + (float)resid[i];
  if (flag[0]) ((__bf16*)out)[i] = (__bf16)v;
  else         ((float*)out)[i] = v;
}

// ---------------- MFMA flash attention, split-KV + T13 defer-max -----------
// R9: defer-max (THR=8): skip the O/l rescale when the tile max doesn't
// exceed the running m by >8. Online softmax stays exact for any consistent
// m (combine uses the stored m); P <= e^8 fits bf16/fp32 comfortably.
__global__ __launch_bounds__(256) void attn_mfma_kernel(
    const __bf16* __restrict__ Q,    // fused base (+0), row stride rs
    const __bf16* __restrict__ Kk,   // fused base + 1280, row stride rs
    const __bf16* __restrict__ Vt,   // [CDIM][VTLD]
    float* __restrict__ Opart,       // [2][SEQ][CDIM]
    float* __restrict__ ml,          // [2][NHEAD][SEQ][2]
    int rs) {
  const int h = blockIdx.y;
  const int q0 = blockIdx.x * 64;
  const int z = blockIdx.z;
  const int tid = threadIdx.x;
  const int wave = tid >> 6, lane = tid & 63;
  const int l16 = lane & 15, quad = lane >> 4;

  __shared__ __bf16 Ks[64 * APAD];
  __shared__ __bf16 Vs[64 * APAD];
  __shared__ __bf16 Ps[4][16 * APAD];

  bf16x8 qf[2];
  {
    int q = q0 + wave * 16 + l16;
    if (q > SEQ - 1) q = SEQ - 1;
    const __bf16* qp = Q + (size_t)q * rs + h * DHEAD + quad * 8;
    qf[0] = *(const bf16x8*)(qp);
    qf[1] = *(const bf16x8*)(qp + 32);
  }

  f32x4 oacc[4];
  const f32x4 zero = {0.f, 0.f, 0.f, 0.f};
#pragma unroll
  for (int jt = 0; jt < 4; ++jt) oacc[jt] = zero;
  float mrow[4], lrow[4];
#pragma unroll
  for (int r = 0; r < 4; ++r) { mrow[r] = -30000.f; lrow[r] = 0.f; }

  const int srow = tid >> 2;
  const int scol = (tid & 3) << 4;

  const __bf16* Kbase = Kk + h * DHEAD;
  const __bf16* Vbase = Vt + (size_t)(h * DHEAD + srow) * VTLD;

  for (int kt = z * 12; kt < z * 12 + 12; ++kt) {
    const int key0 = kt * 64;
    __syncthreads();
    {
      int gk = key0 + srow;
      if (gk > SEQ - 1) gk = SEQ - 1;
      const __bf16* kp = Kbase + (size_t)gk * rs + scol;
      *(bf16x8*)(&Ks[srow * APAD + scol]) = *(const bf16x8*)(kp);
      *(bf16x8*)(&Ks[srow * APAD + scol + 8]) = *(const bf16x8*)(kp + 8);
      const __bf16* vp = Vbase + key0 + scol;
      *(bf16x8*)(&Vs[srow * APAD + scol]) = *(const bf16x8*)(vp);
      *(bf16x8*)(&Vs[srow * APAD + scol + 8]) = *(const bf16x8*)(vp + 8);
    }
    __syncthreads();

    f32x4 s[4];
#pragma unroll
    for (int jt = 0; jt < 4; ++jt) s[jt] = zero;
#pragma unroll
    for (int jt = 0; jt < 4; ++jt)
#pragma unroll
      for (int ks = 0; ks < 2; ++ks) {
        const bf16x8 kf = *(const bf16x8*)(&Ks[(jt * 16 + l16) * APAD + ks * 32 + quad * 8]);
        s[jt] = __builtin_amdgcn_mfma_f32_16x16x32_bf16(qf[ks], kf, s[jt], 0, 0, 0);
      }

#pragma unroll
    for (int jt = 0; jt < 4; ++jt) {
      const int key = key0 + jt * 16 + l16;
#pragma unroll
      for (int r = 0; r < 4; ++r) {
        float sv = s[jt][r] * 0.125f;
        if (key >= SEQ) sv = -30000.f;
        s[jt][r] = sv;
      }
    }

#pragma unroll
    for (int r = 0; r < 4; ++r) {
      float tmax = fmaxf(fmaxf(s[0][r], s[1][r]), fmaxf(s[2][r], s[3][r]));
#pragma unroll
      for (int off = 8; off > 0; off >>= 1) tmax = fmaxf(tmax, __shfl_xor(tmax, off));
      if (tmax > mrow[r] + 8.f) {        // T13 defer-max: rescale only on growth
        const float alpha = __expf(mrow[r] - tmax);
        lrow[r] *= alpha;
#pragma unroll
        for (int jt = 0; jt < 4; ++jt) oacc[jt][r] *= alpha;
        mrow[r] = tmax;
      }
#pragma unroll
      for (int jt = 0; jt < 4; ++jt) {
        const float p = __expf(s[jt][r] - mrow[r]);
        lrow[r] += p;
        Ps[wave][(quad * 4 + r) * APAD + jt * 16 + l16] = (__bf16)p;
      }
    }

    bf16x8 pf[2];
    pf[0] = *(const bf16x8*)(&Ps[wave][l16 * APAD + quad * 8]);
    pf[1] = *(const bf16x8*)(&Ps[wave][l16 * APAD + 32 + quad * 8]);
#pragma unroll
    for (int jt = 0; jt < 4; ++jt)
#pragma unroll
      for (int ks = 0; ks < 2; ++ks) {
        const bf16x8 vf = *(const bf16x8*)(&Vs[(jt * 16 + l16) * APAD + ks * 32 + quad * 8]);
        oacc[jt] = __builtin_amdgcn_mfma_f32_16x16x32_bf16(pf[ks], vf, oacc[jt], 0, 0, 0);
      }
  }

  float* Oz = Opart + (size_t)z * SEQ * CDIM;
#pragma unroll
  for (int r = 0; r < 4; ++r) {
    float lt = lrow[r];
#pragma unroll
    for (int off = 8; off > 0; off >>= 1) lt += __shfl_xor(lt, off);
    const int q = q0 + wave * 16 + quad * 4 + r;
    if (q < SEQ) {
#pragma unroll
      for (int jt = 0; jt < 4; ++jt)
        Oz[(size_t)q * CDIM + h * DHEAD + jt * 16 + l16] = oacc[jt][r];
      if (l16 == 0) {
        const size_t mi = ((size_t)(z * NHEAD + h) * SEQ + q) * 2;
        ml[mi] = mrow[r];
        ml[mi + 1] = lt;
      }
    }
  }
}

// ---------------- combine the two kv-halves --------------------------------
__global__ __launch_bounds__(256) void attn_combine_kernel(
    const float* __restrict__ Op, const float* __restrict__ ml,
    __bf16* __restrict__ O) {
  const int i = blockIdx.x * 256 + threadIdx.x;
  if (i >= SEQ * CDIM) return;
  const int q = i / CDIM;
  const int h = (i % CDIM) >> 6;
  const size_t m1i = ((size_t)h * SEQ + q) * 2;
  const size_t m2i = ((size_t)(NHEAD + h) * SEQ + q) * 2;
  const float m1 = ml[m1i], l1 = ml[m1i + 1];
  const float m2 = ml[m2i], l2 = ml[m2i + 1];
  const float M = fmaxf(m1, m2);
  const float e1 = __expf(m1 - M), e2 = __expf(m2 - M);
  const float v = (e1 * Op[i] + e2 * Op[(size_t)SEQ * CDIM + i]) /
                  (e1 * l1 + e2 * l2);
  O[i] = (__bf16)v;
}

// ---------------- launch ----------------
extern "C" void kernel_launch(void* const* d_in, const int* in_sizes, int n_in,
                              void* d_out, int out_size, void* d_ws, size_t ws_size,
                              hipStream_t stream) {
  const void* x   = d_in[0];
  const void* Wq  = d_in[1];
  const void* bq  = d_in[2];
  const void* Wk  = d_in[3];
  const void* Wv  = d_in[4];
  const void* bv  = d_in[5];
  const void* Wo  = d_in[6];
  const void* bo  = d_in[7];
  const void* g1  = d_in[8];
  const void* be1 = d_in[9];
  const void* g2  = d_in[10];
  const void* be2 = d_in[11];
  const void* W1  = d_in[12];
  const void* bm1 = d_in[13];
  const void* W2  = d_in[14];
  const void* bm2 = d_in[15];

  char* ws = (char*)d_ws;
  size_t off = 0;
  auto alloc = [&](size_t elems) {
    __bf16* p = (__bf16*)(ws + off);
    off += elems * sizeof(__bf16);
    return p;
  };
  __bf16* Wqkvt = alloc((size_t)QKVN * CDIM);   // Wq^T|Wk^T|Wv^T
  __bf16* Wot   = alloc((size_t)CDIM * CDIM);
  __bf16* W1t   = alloc((size_t)CDIM * NMLP);
  __bf16* W2t   = alloc((size_t)CDIM * NMLP);
  __bf16* qkvb  = alloc((size_t)SEQ * QKVN);    // fused q|k|v; later x1|h2
  __bf16* hb    = alloc((size_t)SEQ * CDIM);    // ln1 out / attn out
  __bf16* mb    = alloc((size_t)SEQ * NMLP);    // mlp hidden; head = Vt
  __bf16* pb    = alloc(20480);                 // packed params
  off = (off + 15) & ~(size_t)15;
  float* pscr = (float*)(ws + off);             // O-partials / split-K partials
  off += (size_t)2 * SEQ * CDIM * sizeof(float);
  float* mlb = (float*)(ws + off);              // attn (m,l): 2 x 20 x 1500 x 2
  off += (size_t)2 * NHEAD * SEQ * 2 * sizeof(float);
  int* flag = (int*)(ws + off);

  __bf16* vtb  = mb;                         // Vt[CDIM][VTLD] (dead before MLP1)
  __bf16* x1b  = qkvb;                       // x1 (qkv dead after attention)
  __bf16* h2b  = qkvb + (size_t)SEQ * CDIM;  // ln2 out

  __bf16* qkvbias = pb + 0;
  __bf16* bo_b  = pb + 3840;
  __bf16* g2_b  = pb + 7680;
  __bf16* be2_b = pb + 8960;
  __bf16* b1_b  = pb + 10240;
  __bf16* b2_b  = pb + 15360;

  // 1. fused prologue: pack params + all weight transposes + LN1 (one launch)
  prep_kernel<<<65 + 19200 + SEQ, 256, 0, stream>>>(
      (const unsigned int*)x, x, bq, bv, bo, g1, be1, g2, be2, bm1, bm2,
      Wq, Wk, Wv, Wo, W1, W2, pb, flag, Wqkvt, Wot, W1t, W2t, hb);
  // 2. qkv = h @ Wqkv^T + (bq|0|bv)  [1500][3840], counted-vmcnt 128^2, 360 blk
  gemm128c_kernel<<<360, 256, 0, stream>>>(
      hb, Wqkvt, qkvbias, qkvb, SEQ, QKVN, CDIM, 0, 12);
  // 3. Vt = V^T
  transpose_act_kernel<<<dim3(40, 47), dim3(32, 8), 0, stream>>>(
      qkvb + 2560, vtb, QKVN);
  // 4. attention split-KV partials (z=2, defer-max)
  attn_mfma_kernel<<<dim3(24, NHEAD, 2), 256, 0, stream>>>(
      qkvb, qkvb + 1280, vtb, pscr, mlb, QKVN);
  // 5. combine -> hb
  attn_combine_kernel<<<7500, 256, 0, stream>>>(pscr, mlb, hb);
  // 6. attn @ Wo (split-K=2, fp32 partials), 480 blocks
  gemm64_kernel<<<dim3(24, 10, 2), 256, 0, stream>>>(
      hb, Wot, nullptr, pscr, SEQ, CDIM, CDIM, 640, 0, 2);
  // 7. fused: x1 = x + partials + bo ; h2 = LN2(x1)
  resid_ln_kernel<<<SEQ, 256, 0, stream>>>(pscr, bo_b, x, g2_b, be2_b,
                                           x1b, h2b, flag);
  // 8. m = gelu(h2 @ W1 + b1)  (counted-vmcnt 128^2, 480 blocks)
  gemm128c_kernel<<<480, 256, 0, stream>>>(
      h2b, W1t, b1_b, mb, SEQ, NMLP, CDIM, 1, 12);
  // 9. m @ W2 (split-K=2), 480 blocks
  gemm64_kernel<<<dim3(24, 10, 2), 256, 0, stream>>>(
      mb, W2t, nullptr, pscr, SEQ, CDIM, NMLP, 2560, 0, 2);
  // 10. out = x1 + partials + b2 (output dtype per flag)
  reduce_kernel<<<7500, 256, 0, stream>>>(pscr, b2_b, x1b, d_out,
                                          SEQ * CDIM, CDIM, flag);
}

// Round 11
// 362.587 us; speedup vs baseline: 1.0275x; 1.0275x over previous
//
#include <hip/hip_runtime.h>
#include <hip/hip_bf16.h>
#include <math.h>

typedef __bf16 bf16x8 __attribute__((ext_vector_type(8)));
typedef float f32x4 __attribute__((ext_vector_type(4)));

#define SEQ 1500
#define CDIM 1280
#define NHEAD 20
#define DHEAD 64
#define NMLP 5120
#define QKVN 3840
#define VTLD 1504   // leading dim of transposed V (47*32)
#define APAD 68     // attention LDS stride

#define GLOAD_LDS16(gp, lp)                                                    \
  __builtin_amdgcn_global_load_lds(                                            \
      (const __attribute__((address_space(1))) unsigned int*)(gp),             \
      (__attribute__((address_space(3))) unsigned int*)(lp), 16, 0, 0)

// ---------------- per-block input-dtype detect (1KB ballot vote on x) ------
__device__ __forceinline__ int detect_bf(const unsigned int* __restrict__ xw,
                                         int tid) {
  __shared__ int shdet[4];
  const unsigned int w = xw[tid & 255];
  const unsigned int e = (w >> 7) & 0xFF;
  const unsigned long long b = __ballot(e >= 100 && e <= 150);
  if ((tid & 63) == 0) shdet[tid >> 6] = (int)__popcll(b);
  __syncthreads();
  return (shdet[0] + shdet[1] + shdet[2] + shdet[3]) >= 160;
}

// ---------------- fused prologue: pack + all weight transposes + LN1 -------
// (R9 fusion, measured neutral vs 3 launches; kept for fewer launches.)
// pb layout: [0,3840) qkvbias (bq|0|bv) | 3840 bo | 5120 g1 | 6400 be1 |
//            7680 g2 | 8960 be2 | 10240 b1(5120) | 15360 b2
__device__ __forceinline__ void transpose_body(const void* in, __bf16* out,
                                               int K, int N, int isbf,
                                               int bx, int by, int tid) {
  __shared__ __bf16 t[32][33];
  const int tx = tid & 31, ty = tid >> 5;
  const int n0 = bx * 32, k0 = by * 32;
  if (isbf) {
    const __bf16* s = (const __bf16*)in;
#pragma unroll
    for (int i = ty; i < 32; i += 8)
      t[i][tx] = s[(size_t)(k0 + i) * N + n0 + tx];
  } else {
    const float* s = (const float*)in;
#pragma unroll
    for (int i = ty; i < 32; i += 8)
      t[i][tx] = (__bf16)s[(size_t)(k0 + i) * N + n0 + tx];
  }
  __syncthreads();
#pragma unroll
  for (int i = ty; i < 32; i += 8)
    out[(size_t)(n0 + i) * K + k0 + tx] = t[tx][i];
}

__global__ __launch_bounds__(256) void prep_kernel(
    const unsigned int* __restrict__ xw, const void* __restrict__ X,
    const void* bq, const void* bv, const void* bo,
    const void* g1, const void* be1, const void* g2, const void* be2,
    const void* b1, const void* b2,
    const void* Wq, const void* Wk, const void* Wv, const void* Wo,
    const void* W1, const void* W2,
    __bf16* __restrict__ pb, int* __restrict__ flag,
    __bf16* __restrict__ Wqkvt, __bf16* __restrict__ Wot,
    __bf16* __restrict__ W1t, __bf16* __restrict__ W2t,
    __bf16* __restrict__ Y) {
  const int tid = threadIdx.x;
  const int isbf = detect_bf(xw, tid);
  auto ld = [&](const void* p, int j) -> float {
    return isbf ? (float)((const __bf16*)p)[j] : ((const float*)p)[j];
  };
  const int id = blockIdx.x;

  if (id < 65) {
    // ---- pack params ----
    if (id == 0 && tid == 0) flag[0] = isbf;
    const int i = id * 256 + tid;
    if (i >= 16640) return;
    float v;
    if (i < 3840) {
      if (i < 1280) v = ld(bq, i);
      else if (i < 2560) v = 0.f;
      else v = ld(bv, i - 2560);
    } else if (i < 5120) v = ld(bo, i - 3840);
    else if (i < 6400) v = ld(g1, i - 5120);
    else if (i < 7680) v = ld(be1, i - 6400);
    else if (i < 8960) v = ld(g2, i - 7680);
    else if (i < 10240) v = ld(be2, i - 8960);
    else if (i < 15360) v = ld(b1, i - 10240);
    else v = ld(b2, i - 15360);
    pb[i] = (__bf16)v;
  } else if (id < 65 + 19200) {
    // ---- weight transposes ----
    const int wid = id - 65;
    if (wid < 6400) {                     // Wq|Wk|Wv|Wo : 4 x (40x40)
      const int w = wid / 1600, r = wid % 1600;
      const void* in = (w == 0) ? Wq : (w == 1) ? Wk : (w == 2) ? Wv : Wo;
      __bf16* out = (w < 3) ? (Wqkvt + (size_t)w * CDIM * CDIM) : Wot;
      transpose_body(in, out, CDIM, CDIM, isbf, r % 40, r / 40, tid);
    } else if (wid < 12800) {             // W1 : 160x40
      const int r = wid - 6400;
      transpose_body(W1, W1t, CDIM, NMLP, isbf, r % 160, r / 160, tid);
    } else {                              // W2 : 40x160
      const int r = wid - 12800;
      transpose_body(W2, W2t, NMLP, CDIM, isbf, r % 40, r / 40, tid);
    }
  } else {
    // ---- LN1 ----
    const int row = id - (65 + 19200);
    const int isf32 = !isbf;
    float v[5];
    float s = 0.f, s2 = 0.f;
#pragma unroll
    for (int i = 0; i < 5; ++i) {
      const int c = tid + 256 * i;
      const size_t idx = (size_t)row * CDIM + c;
      v[i] = isf32 ? ((const float*)X)[idx] : (float)((const __bf16*)X)[idx];
      s += v[i];
      s2 += v[i] * v[i];
    }
    const int lane = tid & 63, wv = tid >> 6;
#pragma unroll
    for (int off = 32; off > 0; off >>= 1) {
      s += __shfl_down(s, off);
      s2 += __shfl_down(s2, off);
    }
    __shared__ float red[8];
    if (lane == 0) { red[wv] = s; red[4 + wv] = s2; }
    __syncthreads();
    s = red[0] + red[1] + red[2] + red[3];
    s2 = red[4] + red[5] + red[6] + red[7];
    const float mu = s * (1.f / CDIM);
    const float var = s2 * (1.f / CDIM) - mu * mu;
    const float rstd = rsqrtf(fmaxf(var, 0.f) + 1e-5f);
#pragma unroll
    for (int i = 0; i < 5; ++i) {
      const int c = tid + 256 * i;
      Y[(size_t)row * CDIM + c] =
          (__bf16)((v[i] - mu) * rstd * ld(g1, c) + ld(be1, c));
    }
  }
}

// ---------------- activation transpose: [SEQ][.] -> [N][VTLD] --------------
__global__ __launch_bounds__(256) void transpose_act_kernel(const __bf16* __restrict__ in,
                                                            __bf16* __restrict__ out,
                                                            int istride) {
  __shared__ __bf16 t[32][33];
  const int tx = threadIdx.x, ty = threadIdx.y;
  const int n0 = blockIdx.x * 32, k0 = blockIdx.y * 32;
#pragma unroll
  for (int i = ty; i < 32; i += 8) {
    const int k = k0 + i;
    t[i][tx] = (k < SEQ) ? in[(size_t)k * istride + n0 + tx] : (__bf16)0.f;
  }
  __syncthreads();
#pragma unroll
  for (int i = ty; i < 32; i += 8) {
    const int kk = k0 + tx;
    if (kk < VTLD) out[(size_t)(n0 + i) * VTLD + kk] = t[tx][i];
  }
}

// ---------------- fused: x1 = x + sum(P) + bo ; h2 = LN2(x1) ----------------
__global__ __launch_bounds__(256) void resid_ln_kernel(
    const float* __restrict__ P, const __bf16* __restrict__ bo,
    const void* __restrict__ X, const __bf16* __restrict__ gamma,
    const __bf16* __restrict__ beta, __bf16* __restrict__ X1,
    __bf16* __restrict__ H2, const int* __restrict__ flag) {
  const int isf32 = (flag[0] == 0);
  const int row = blockIdx.x;
  const int MN = SEQ * CDIM;
  float v[5];
  float s = 0.f, s2 = 0.f;
#pragma unroll
  for (int i = 0; i < 5; ++i) {
    const int c = threadIdx.x + 256 * i;
    const size_t idx = (size_t)row * CDIM + c;
    const float xv = isf32 ? ((const float*)X)[idx] : (float)((const __bf16*)X)[idx];
    const float val = P[idx] + P[MN + idx] + (float)bo[c] + xv;
    X1[idx] = (__bf16)val;
    v[i] = val;
    s += val;
    s2 += val * val;
  }
  const int lane = threadIdx.x & 63, wv = threadIdx.x >> 6;
#pragma unroll
  for (int off = 32; off > 0; off >>= 1) {
    s += __shfl_down(s, off);
    s2 += __shfl_down(s2, off);
  }
  __shared__ float red[8];
  if (lane == 0) { red[wv] = s; red[4 + wv] = s2; }
  __syncthreads();
  s = red[0] + red[1] + red[2] + red[3];
  s2 = red[4] + red[5] + red[6] + red[7];
  const float mu = s * (1.f / CDIM);
  const float var = s2 * (1.f / CDIM) - mu * mu;
  const float rstd = rsqrtf(fmaxf(var, 0.f) + 1e-5f);
#pragma unroll
  for (int i = 0; i < 5; ++i) {
    const int c = threadIdx.x + 256 * i;
    H2[(size_t)row * CDIM + c] =
        (__bf16)((v[i] - mu) * rstd * (float)gamma[c] + (float)beta[c]);
  }
}

// ---------------- GEMM 64x128 tile, BK=64 (2 x 32 chunks), 2-barrier -------
// (R5 structure, proven). nsplit>1: fp32 partials. Used for Wo / MLP2.
__global__ __launch_bounds__(256) void gemm64_kernel(
    const __bf16* __restrict__ A, const __bf16* __restrict__ Bt,
    const __bf16* __restrict__ bias, void* __restrict__ Cv,
    int M, int N, int K, int KS, int gelu, int nsplit) {
  __shared__ __bf16 As[2][64 * 32];
  __shared__ __bf16 Bs[2][128 * 32];
  const int bm = blockIdx.x, bn = blockIdx.y, sz = blockIdx.z;
  const int tid = threadIdx.x;
  const int lane = tid & 63, wave = tid >> 6;
  const int l16 = lane & 15, kq = (lane >> 4) << 3;
  const int lrow = lane >> 2, lcol = (lane & 3) << 3;
  const int wn = wave * 32;

  f32x4 acc[4][2];
  const f32x4 zero = {0.f, 0.f, 0.f, 0.f};
#pragma unroll
  for (int i = 0; i < 4; ++i)
#pragma unroll
    for (int j = 0; j < 2; ++j) acc[i][j] = zero;

  const int kbeg = sz * KS;
  int kend = kbeg + KS;
  if (kend > K) kend = K;

  int ga = bm * 64 + wave * 16 + lrow;
  if (ga > M - 1) ga = M - 1;  // clamp: garbage rows never stored
  const __bf16* Ap = A + (size_t)ga * K + lcol;

  for (int k0 = kbeg; k0 < kend; k0 += 64) {
#pragma unroll
    for (int c = 0; c < 2; ++c)
      GLOAD_LDS16(Ap + k0 + c * 32, &As[c][wave * 512]);
#pragma unroll
    for (int c = 0; c < 2; ++c)
#pragma unroll
      for (int t = 0; t < 2; ++t) {
        const int seg = t * 4 + wave;
        const int gb = bn * 128 + seg * 16 + lrow;  // N multiple of 128
        GLOAD_LDS16(Bt + (size_t)gb * K + k0 + c * 32 + lcol, &Bs[c][seg * 512]);
      }
    __syncthreads();
    bf16x8 af[4][2], bfr[2][2];
#pragma unroll
    for (int i = 0; i < 4; ++i)
#pragma unroll
      for (int c = 0; c < 2; ++c)
        af[i][c] = *(const bf16x8*)(&As[c][(i * 16 + l16) * 32 + kq]);
#pragma unroll
    for (int j = 0; j < 2; ++j)
#pragma unroll
      for (int c = 0; c < 2; ++c)
        bfr[j][c] = *(const bf16x8*)(&Bs[c][(wn + j * 16 + l16) * 32 + kq]);
#pragma unroll
    for (int i = 0; i < 4; ++i)
#pragma unroll
      for (int j = 0; j < 2; ++j)
#pragma unroll
        for (int c = 0; c < 2; ++c)
          acc[i][j] = __builtin_amdgcn_mfma_f32_16x16x32_bf16(af[i][c], bfr[j][c],
                                                              acc[i][j], 0, 0, 0);
    __syncthreads();
  }

  const int rq4 = (lane >> 4) * 4;
  if (nsplit > 1) {
    float* P = (float*)Cv + (size_t)sz * M * N;
#pragma unroll
    for (int i = 0; i < 4; ++i)
#pragma unroll
      for (int r = 0; r < 4; ++r) {
        const int grow = bm * 64 + i * 16 + rq4 + r;
        if (grow >= M) continue;
#pragma unroll
        for (int j = 0; j < 2; ++j) {
          const int gcol = bn * 128 + wn + j * 16 + l16;
          P[(size_t)grow * N + gcol] = acc[i][j][r];
        }
      }
  } else {
    __bf16* Cb = (__bf16*)Cv;
#pragma unroll
    for (int i = 0; i < 4; ++i)
#pragma unroll
      for (int r = 0; r < 4; ++r) {
        const int grow = bm * 64 + i * 16 + rq4 + r;
        if (grow >= M) continue;
#pragma unroll
        for (int j = 0; j < 2; ++j) {
          const int gcol = bn * 128 + wn + j * 16 + l16;
          float vv = acc[i][j][r];
          if (bias) vv += (float)bias[gcol];
          if (gelu) vv = 0.5f * vv * (1.f + erff(vv * 0.70710678118654752f));
          Cb[(size_t)grow * N + gcol] = (__bf16)vv;
        }
      }
  }
}

// ---------------- GEMM 128x128, BK=64, counted-vmcnt dbuf (R5 win) ---------
__global__ __launch_bounds__(256, 2) void gemm128c_kernel(
    const __bf16* __restrict__ A, const __bf16* __restrict__ Bt,
    const __bf16* __restrict__ bias, __bf16* __restrict__ C,
    int M, int N, int K, int gelu, int mtiles) {
  __shared__ __bf16 As[2][128 * 64];   // 16 KiB per buf
  __shared__ __bf16 Bs[2][128 * 64];

  // bijective XCD swizzle (m204)
  const int nwg = mtiles * (N >> 7);
  const int qq = nwg >> 3, rr = nwg & 7;
  const int xcd = blockIdx.x & 7, rk = blockIdx.x >> 3;
  const int wg = (xcd < rr ? xcd * (qq + 1) : rr * (qq + 1) + (xcd - rr) * qq) + rk;
  const int bm = wg % mtiles, bn = wg / mtiles;

  const int tid = threadIdx.x;
  const int lane = tid & 63, wave = tid >> 6;
  const int wm = (wave >> 1) * 64, wn = (wave & 1) * 64;   // 2x2 wave grid
  const int l16 = lane & 15, quad = lane >> 4;

  const int rT = tid >> 3, sl = tid & 7;
  const int aoff = ((sl * 16) ^ ((rT & 7) << 4)) >> 1;     // elems
  const __bf16* Ap[4];
  const __bf16* Bp[4];
#pragma unroll
  for (int s = 0; s < 4; ++s) {
    int gm = bm * 128 + s * 32 + rT;
    if (gm > M - 1) gm = M - 1;      // clamp: garbage rows never stored
    Ap[s] = A + (size_t)gm * K + aoff;
    Bp[s] = Bt + (size_t)(bn * 128 + s * 32 + rT) * K + aoff;
  }
  const int ldst = tid * 8;

  const int xsw = (l16 & 7) << 4;
  const int kb0 = ((quad << 4) ^ xsw) >> 1;
  const int kb1 = (((quad << 4) + 64) ^ xsw) >> 1;

  f32x4 acc[4][4];
  const f32x4 zero = {0.f, 0.f, 0.f, 0.f};
#pragma unroll
  for (int i = 0; i < 4; ++i)
#pragma unroll
    for (int j = 0; j < 4; ++j) acc[i][j] = zero;

  const int NT = K >> 6;

#define STAGE128(b, k0)                                       \
  do {                                                        \
    _Pragma("unroll")                                         \
    for (int s = 0; s < 4; ++s) {                             \
      GLOAD_LDS16(Ap[s] + (k0), &As[b][s * 2048 + ldst]);     \
      GLOAD_LDS16(Bp[s] + (k0), &Bs[b][s * 2048 + ldst]);     \
    }                                                         \
  } while (0)

  STAGE128(0, 0);
  for (int t = 0; t < NT; ++t) {
    const int cur = t & 1;
    if (t + 1 < NT) {
      STAGE128(cur ^ 1, (t + 1) * 64);
      asm volatile("s_waitcnt vmcnt(8)" ::: "memory");
    } else {
      asm volatile("s_waitcnt vmcnt(0)" ::: "memory");
    }
    __builtin_amdgcn_s_barrier();
    __builtin_amdgcn_sched_barrier(0);
    bf16x8 af[4][2], bfr[4][2];
#pragma unroll
    for (int i = 0; i < 4; ++i) {
      const int row = (wm + i * 16 + l16) * 64;
      af[i][0] = *(const bf16x8*)(&As[cur][row + kb0]);
      af[i][1] = *(const bf16x8*)(&As[cur][row + kb1]);
    }
#pragma unroll
    for (int j = 0; j < 4; ++j) {
      const int row = (wn + j * 16 + l16) * 64;
      bfr[j][0] = *(const bf16x8*)(&Bs[cur][row + kb0]);
      bfr[j][1] = *(const bf16x8*)(&Bs[cur][row + kb1]);
    }
    __builtin_amdgcn_s_setprio(1);
#pragma unroll
    for (int i = 0; i < 4; ++i)
#pragma unroll
      for (int j = 0; j < 4; ++j)
#pragma unroll
        for (int c = 0; c < 2; ++c)
          acc[i][j] = __builtin_amdgcn_mfma_f32_16x16x32_bf16(af[i][c], bfr[j][c],
                                                              acc[i][j], 0, 0, 0);
    __builtin_amdgcn_s_setprio(0);
    __builtin_amdgcn_s_barrier();
    __builtin_amdgcn_sched_barrier(0);
  }
#undef STAGE128

#pragma unroll
  for (int i = 0; i < 4; ++i)
#pragma unroll
    for (int r = 0; r < 4; ++r) {
      const int grow = bm * 128 + wm + i * 16 + quad * 4 + r;
      if (grow >= M) continue;
#pragma unroll
      for (int j = 0; j < 4; ++j) {
        const int gcol = bn * 128 + wn + j * 16 + l16;
        float vv = acc[i][j][r];
        if (bias) vv += (float)bias[gcol];
        if (gelu) vv = 0.5f * vv * (1.f + erff(vv * 0.70710678118654752f));
        C[(size_t)grow * N + gcol] = (__bf16)vv;
      }
    }
}

// ---------------- final reduce: out = resid + sum(P) + bias ----------------
__global__ __launch_bounds__(256) void reduce_kernel(
    const float* __restrict__ P, const __bf16* __restrict__ bias,
    const __bf16* __restrict__ resid, void* __restrict__ out,
    int MN, int N, const int* __restrict__ flag) {
  const int i = blockIdx.x * 256 + threadIdx.x;
  if (i >= MN) return;
  const float v = P[i] + P[(size_t)MN + i] + (float)bias[i % N] + (float)resid[i];
  if (flag[0]) ((__bf16*)out)[i] = (__bf16)v;
  else         ((float*)out)[i] = v;
}

// ---------------- MFMA flash attention, split-KV (R5 exact) ----------------
// R11: defer-max REVERTED (divergent per-quad branch cost +11 us, R10).
// Unconditional rescale restored.
__global__ __launch_bounds__(256) void attn_mfma_kernel(
    const __bf16* __restrict__ Q,    // fused base (+0), row stride rs
    const __bf16* __restrict__ Kk,   // fused base + 1280, row stride rs
    const __bf16* __restrict__ Vt,   // [CDIM][VTLD]
    float* __restrict__ Opart,       // [2][SEQ][CDIM]
    float* __restrict__ ml,          // [2][NHEAD][SEQ][2]
    int rs) {
  const int h = blockIdx.y;
  const int q0 = blockIdx.x * 64;
  const int z = blockIdx.z;
  const int tid = threadIdx.x;
  const int wave = tid >> 6, lane = tid & 63;
  const int l16 = lane & 15, quad = lane >> 4;

  __shared__ __bf16 Ks[64 * APAD];
  __shared__ __bf16 Vs[64 * APAD];
  __shared__ __bf16 Ps[4][16 * APAD];

  bf16x8 qf[2];
  {
    int q = q0 + wave * 16 + l16;
    if (q > SEQ - 1) q = SEQ - 1;
    const __bf16* qp = Q + (size_t)q * rs + h * DHEAD + quad * 8;
    qf[0] = *(const bf16x8*)(qp);
    qf[1] = *(const bf16x8*)(qp + 32);
  }

  f32x4 oacc[4];
  const f32x4 zero = {0.f, 0.f, 0.f, 0.f};
#pragma unroll
  for (int jt = 0; jt < 4; ++jt) oacc[jt] = zero;
  float mrow[4], lrow[4];
#pragma unroll
  for (int r = 0; r < 4; ++r) { mrow[r] = -30000.f; lrow[r] = 0.f; }

  const int srow = tid >> 2;
  const int scol = (tid & 3) << 4;

  const __bf16* Kbase = Kk + h * DHEAD;
  const __bf16* Vbase = Vt + (size_t)(h * DHEAD + srow) * VTLD;

  for (int kt = z * 12; kt < z * 12 + 12; ++kt) {
    const int key0 = kt * 64;
    __syncthreads();
    {
      int gk = key0 + srow;
      if (gk > SEQ - 1) gk = SEQ - 1;
      const __bf16* kp = Kbase + (size_t)gk * rs + scol;
      *(bf16x8*)(&Ks[srow * APAD + scol]) = *(const bf16x8*)(kp);
      *(bf16x8*)(&Ks[srow * APAD + scol + 8]) = *(const bf16x8*)(kp + 8);
      const __bf16* vp = Vbase + key0 + scol;
      *(bf16x8*)(&Vs[srow * APAD + scol]) = *(const bf16x8*)(vp);
      *(bf16x8*)(&Vs[srow * APAD + scol + 8]) = *(const bf16x8*)(vp + 8);
    }
    __syncthreads();

    f32x4 s[4];
#pragma unroll
    for (int jt = 0; jt < 4; ++jt) s[jt] = zero;
#pragma unroll
    for (int jt = 0; jt < 4; ++jt)
#pragma unroll
      for (int ks = 0; ks < 2; ++ks) {
        const bf16x8 kf = *(const bf16x8*)(&Ks[(jt * 16 + l16) * APAD + ks * 32 + quad * 8]);
        s[jt] = __builtin_amdgcn_mfma_f32_16x16x32_bf16(qf[ks], kf, s[jt], 0, 0, 0);
      }

#pragma unroll
    for (int jt = 0; jt < 4; ++jt) {
      const int key = key0 + jt * 16 + l16;
#pragma unroll
      for (int r = 0; r < 4; ++r) {
        float sv = s[jt][r] * 0.125f;
        if (key >= SEQ) sv = -30000.f;
        s[jt][r] = sv;
      }
    }

#pragma unroll
    for (int r = 0; r < 4; ++r) {
      float tmax = fmaxf(fmaxf(s[0][r], s[1][r]), fmaxf(s[2][r], s[3][r]));
#pragma unroll
      for (int off = 8; off > 0; off >>= 1) tmax = fmaxf(tmax, __shfl_xor(tmax, off));
      const float mnew = fmaxf(mrow[r], tmax);
      const float alpha = __expf(mrow[r] - mnew);
      mrow[r] = mnew;
      lrow[r] *= alpha;
#pragma unroll
      for (int jt = 0; jt < 4; ++jt) oacc[jt][r] *= alpha;
#pragma unroll
      for (int jt = 0; jt < 4; ++jt) {
        const float p = __expf(s[jt][r] - mnew);
        lrow[r] += p;
        Ps[wave][(quad * 4 + r) * APAD + jt * 16 + l16] = (__bf16)p;
      }
    }

    bf16x8 pf[2];
    pf[0] = *(const bf16x8*)(&Ps[wave][l16 * APAD + quad * 8]);
    pf[1] = *(const bf16x8*)(&Ps[wave][l16 * APAD + 32 + quad * 8]);
#pragma unroll
    for (int jt = 0; jt < 4; ++jt)
#pragma unroll
      for (int ks = 0; ks < 2; ++ks) {
        const bf16x8 vf = *(const bf16x8*)(&Vs[(jt * 16 + l16) * APAD + ks * 32 + quad * 8]);
        oacc[jt] = __builtin_amdgcn_mfma_f32_16x16x32_bf16(pf[ks], vf, oacc[jt], 0, 0, 0);
      }
  }

  float* Oz = Opart + (size_t)z * SEQ * CDIM;
#pragma unroll
  for (int r = 0; r < 4; ++r) {
    float lt = lrow[r];
#pragma unroll
    for (int off = 8; off > 0; off >>= 1) lt += __shfl_xor(lt, off);
    const int q = q0 + wave * 16 + quad * 4 + r;
    if (q < SEQ) {
#pragma unroll
      for (int jt = 0; jt < 4; ++jt)
        Oz[(size_t)q * CDIM + h * DHEAD + jt * 16 + l16] = oacc[jt][r];
      if (l16 == 0) {
        const size_t mi = ((size_t)(z * NHEAD + h) * SEQ + q) * 2;
        ml[mi] = mrow[r];
        ml[mi + 1] = lt;
      }
    }
  }
}

// ---------------- combine the two kv-halves --------------------------------
__global__ __launch_bounds__(256) void attn_combine_kernel(
    const float* __restrict__ Op, const float* __restrict__ ml,
    __bf16* __restrict__ O) {
  const int i = blockIdx.x * 256 + threadIdx.x;
  if (i >= SEQ * CDIM) return;
  const int q = i / CDIM;
  const int h = (i % CDIM) >> 6;
  const size_t m1i = ((size_t)h * SEQ + q) * 2;
  const size_t m2i = ((size_t)(NHEAD + h) * SEQ + q) * 2;
  const float m1 = ml[m1i], l1 = ml[m1i + 1];
  const float m2 = ml[m2i], l2 = ml[m2i + 1];
  const float M = fmaxf(m1, m2);
  const float e1 = __expf(m1 - M), e2 = __expf(m2 - M);
  const float v = (e1 * Op[i] + e2 * Op[(size_t)SEQ * CDIM + i]) /
                  (e1 * l1 + e2 * l2);
  O[i] = (__bf16)v;
}

// ---------------- launch ----------------
extern "C" void kernel_launch(void* const* d_in, const int* in_sizes, int n_in,
                              void* d_out, int out_size, void* d_ws, size_t ws_size,
                              hipStream_t stream) {
  const void* x   = d_in[0];
  const void* Wq  = d_in[1];
  const void* bq  = d_in[2];
  const void* Wk  = d_in[3];
  const void* Wv  = d_in[4];
  const void* bv  = d_in[5];
  const void* Wo  = d_in[6];
  const void* bo  = d_in[7];
  const void* g1  = d_in[8];
  const void* be1 = d_in[9];
  const void* g2  = d_in[10];
  const void* be2 = d_in[11];
  const void* W1  = d_in[12];
  const void* bm1 = d_in[13];
  const void* W2  = d_in[14];
  const void* bm2 = d_in[15];

  char* ws = (char*)d_ws;
  size_t off = 0;
  auto alloc = [&](size_t elems) {
    __bf16* p = (__bf16*)(ws + off);
    off += elems * sizeof(__bf16);
    return p;
  };
  __bf16* Wqkvt = alloc((size_t)QKVN * CDIM);   // Wq^T|Wk^T|Wv^T
  __bf16* Wot   = alloc((size_t)CDIM * CDIM);
  __bf16* W1t   = alloc((size_t)CDIM * NMLP);
  __bf16* W2t   = alloc((size_t)CDIM * NMLP);
  __bf16* qkvb  = alloc((size_t)SEQ * QKVN);    // fused q|k|v; later x1|h2
  __bf16* hb    = alloc((size_t)SEQ * CDIM);    // ln1 out / attn out
  __bf16* mb    = alloc((size_t)SEQ * NMLP);    // mlp hidden; head = Vt
  __bf16* pb    = alloc(20480);                 // packed params
  off = (off + 15) & ~(size_t)15;
  float* pscr = (float*)(ws + off);             // O-partials / split-K partials
  off += (size_t)2 * SEQ * CDIM * sizeof(float);
  float* mlb = (float*)(ws + off);              // attn (m,l): 2 x 20 x 1500 x 2
  off += (size_t)2 * NHEAD * SEQ * 2 * sizeof(float);
  int* flag = (int*)(ws + off);

  __bf16* vtb  = mb;                         // Vt[CDIM][VTLD] (dead before MLP1)
  __bf16* x1b  = qkvb;                       // x1 (qkv dead after attention)
  __bf16* h2b  = qkvb + (size_t)SEQ * CDIM;  // ln2 out

  __bf16* qkvbias = pb + 0;
  __bf16* bo_b  = pb + 3840;
  __bf16* g2_b  = pb + 7680;
  __bf16* be2_b = pb + 8960;
  __bf16* b1_b  = pb + 10240;
  __bf16* b2_b  = pb + 15360;

  // 1. fused prologue: pack params + all weight transposes + LN1 (one launch)
  prep_kernel<<<65 + 19200 + SEQ, 256, 0, stream>>>(
      (const unsigned int*)x, x, bq, bv, bo, g1, be1, g2, be2, bm1, bm2,
      Wq, Wk, Wv, Wo, W1, W2, pb, flag, Wqkvt, Wot, W1t, W2t, hb);
  // 2. qkv = h @ Wqkv^T + (bq|0|bv)  [1500][3840], counted-vmcnt 128^2, 360 blk
  gemm128c_kernel<<<360, 256, 0, stream>>>(
      hb, Wqkvt, qkvbias, qkvb, SEQ, QKVN, CDIM, 0, 12);
  // 3. Vt = V^T
  transpose_act_kernel<<<dim3(40, 47), dim3(32, 8), 0, stream>>>(
      qkvb + 2560, vtb, QKVN);
  // 4. attention split-KV partials (R5 exact, z=2)
  attn_mfma_kernel<<<dim3(24, NHEAD, 2), 256, 0, stream>>>(
      qkvb, qkvb + 1280, vtb, pscr, mlb, QKVN);
  // 5. combine -> hb
  attn_combine_kernel<<<7500, 256, 0, stream>>>(pscr, mlb, hb);
  // 6. attn @ Wo (split-K=2, fp32 partials), 480 blocks
  gemm64_kernel<<<dim3(24, 10, 2), 256, 0, stream>>>(
      hb, Wot, nullptr, pscr, SEQ, CDIM, CDIM, 640, 0, 2);
  // 7. fused: x1 = x + partials + bo ; h2 = LN2(x1)
  resid_ln_kernel<<<SEQ, 256, 0, stream>>>(pscr, bo_b, x, g2_b, be2_b,
                                           x1b, h2b, flag);
  // 8. m = gelu(h2 @ W1 + b1)  (counted-vmcnt 128^2, 480 blocks)
  gemm128c_kernel<<<480, 256, 0, stream>>>(
      h2b, W1t, b1_b, mb, SEQ, NMLP, CDIM, 1, 12);
  // 9. m @ W2 (split-K=2), 480 blocks
  gemm64_kernel<<<dim3(24, 10, 2), 256, 0, stream>>>(
      mb, W2t, nullptr, pscr, SEQ, CDIM, NMLP, 2560, 0, 2);
  // 10. out = x1 + partials + b2 (output dtype per flag)
  reduce_kernel<<<7500, 256, 0, stream>>>(pscr, b2_b, x1b, d_out,
                                          SEQ * CDIM, CDIM, flag);
}

// Round 12
// 339.083 us; speedup vs baseline: 1.0988x; 1.0693x over previous
//
#include <hip/hip_runtime.h>
#include <hip/hip_bf16.h>
#include <math.h>

typedef __bf16 bf16x8 __attribute__((ext_vector_type(8)));
typedef float f32x4 __attribute__((ext_vector_type(4)));

#define SEQ 1500
#define CDIM 1280
#define NHEAD 20
#define DHEAD 64
#define NMLP 5120
#define QKVN 3840
#define VTLD 1504   // leading dim of transposed V (47*32)
#define APAD 68     // attention LDS stride

#define GLOAD_LDS16(gp, lp)                                                    \
  __builtin_amdgcn_global_load_lds(                                            \
      (const __attribute__((address_space(1))) unsigned int*)(gp),             \
      (__attribute__((address_space(3))) unsigned int*)(lp), 16, 0, 0)

// ---------------- per-block input-dtype detect (1KB ballot vote on x) ------
__device__ __forceinline__ int detect_bf(const unsigned int* __restrict__ xw,
                                         int tid) {
  __shared__ int shdet[4];
  const unsigned int w = xw[tid & 255];
  const unsigned int e = (w >> 7) & 0xFF;
  const unsigned long long b = __ballot(e >= 100 && e <= 150);
  if ((tid & 63) == 0) shdet[tid >> 6] = (int)__popcll(b);
  __syncthreads();
  return (shdet[0] + shdet[1] + shdet[2] + shdet[3]) >= 160;
}

// ---------------- vectorized 64x64 transpose tile (R12) --------------------
// R11 profile: prep = 50us @1.75 TB/s, scalar bf16 loads (Common-mistake #2).
// This version: 16B reads (bf16x8 / float4), 16B coalesced writes, LDS
// [64][66] (stride 66 -> gather 4-way conflict max, store 2-way = free).
__device__ __forceinline__ void transpose64(const void* in, __bf16* out,
                                            int K, int N, int isbf,
                                            int bx, int by, int tid) {
  __shared__ __bf16 t[64 * 66];
  const int n0 = bx * 64, k0 = by * 64;
  if (isbf) {
    const __bf16* s = (const __bf16*)in;
    const int kr = tid >> 3, c = (tid & 7) * 8;    // 32 rows/pass, 8 elems
#pragma unroll
    for (int it = 0; it < 2; ++it) {
      const int k = kr + it * 32;
      const bf16x8 v = *(const bf16x8*)(&s[(size_t)(k0 + k) * N + n0 + c]);
      __bf16* d = &t[k * 66 + c];
#pragma unroll
      for (int j = 0; j < 8; ++j) d[j] = v[j];
    }
  } else {
    const float* s = (const float*)in;
    const int kr = tid >> 4, c = (tid & 15) * 4;   // 16 rows/pass, 4 elems
#pragma unroll
    for (int it = 0; it < 4; ++it) {
      const int k = kr + it * 16;
      const float4 v = *(const float4*)(&s[(size_t)(k0 + k) * N + n0 + c]);
      __bf16* d = &t[k * 66 + c];
      d[0] = (__bf16)v.x; d[1] = (__bf16)v.y;
      d[2] = (__bf16)v.z; d[3] = (__bf16)v.w;
    }
  }
  __syncthreads();
  const int nr = tid >> 3, kc = (tid & 7) * 8;
#pragma unroll
  for (int it = 0; it < 2; ++it) {
    const int n = nr + it * 32;
    bf16x8 v;
#pragma unroll
    for (int j = 0; j < 8; ++j) v[j] = t[(kc + j) * 66 + n];
    *(bf16x8*)(&out[(size_t)(n0 + n) * K + k0 + kc]) = v;
  }
}

// ---------------- fused prologue: pack + all weight transposes + LN1 -------
// pb layout: [0,3840) qkvbias (bq|0|bv) | 3840 bo | 5120 g1 | 6400 be1 |
//            7680 g2 | 8960 be2 | 10240 b1(5120) | 15360 b2
// grid: 65 pack | 4800 transpose tiles (4x400 qkvo + 1600 W1 + 1600 W2) |
//       1500 LN1  = 6365 blocks
__global__ __launch_bounds__(256) void prep_kernel(
    const unsigned int* __restrict__ xw, const void* __restrict__ X,
    const void* bq, const void* bv, const void* bo,
    const void* g1, const void* be1, const void* g2, const void* be2,
    const void* b1, const void* b2,
    const void* Wq, const void* Wk, const void* Wv, const void* Wo,
    const void* W1, const void* W2,
    __bf16* __restrict__ pb, int* __restrict__ flag,
    __bf16* __restrict__ Wqkvt, __bf16* __restrict__ Wot,
    __bf16* __restrict__ W1t, __bf16* __restrict__ W2t,
    __bf16* __restrict__ Y) {
  const int tid = threadIdx.x;
  const int isbf = detect_bf(xw, tid);
  auto ld = [&](const void* p, int j) -> float {
    return isbf ? (float)((const __bf16*)p)[j] : ((const float*)p)[j];
  };
  const int id = blockIdx.x;

  if (id < 65) {
    // ---- pack params ----
    if (id == 0 && tid == 0) flag[0] = isbf;
    const int i = id * 256 + tid;
    if (i >= 16640) return;
    float v;
    if (i < 3840) {
      if (i < 1280) v = ld(bq, i);
      else if (i < 2560) v = 0.f;
      else v = ld(bv, i - 2560);
    } else if (i < 5120) v = ld(bo, i - 3840);
    else if (i < 6400) v = ld(g1, i - 5120);
    else if (i < 7680) v = ld(be1, i - 6400);
    else if (i < 8960) v = ld(g2, i - 7680);
    else if (i < 10240) v = ld(be2, i - 8960);
    else if (i < 15360) v = ld(b1, i - 10240);
    else v = ld(b2, i - 15360);
    pb[i] = (__bf16)v;
  } else if (id < 65 + 4800) {
    // ---- weight transposes (64x64 tiles) ----
    const int wid = id - 65;
    if (wid < 1600) {                     // Wq|Wk|Wv|Wo : 4 x (20x20)
      const int w = wid / 400, r = wid % 400;
      const void* in = (w == 0) ? Wq : (w == 1) ? Wk : (w == 2) ? Wv : Wo;
      __bf16* out = (w < 3) ? (Wqkvt + (size_t)w * CDIM * CDIM) : Wot;
      transpose64(in, out, CDIM, CDIM, isbf, r % 20, r / 20, tid);
    } else if (wid < 3200) {              // W1 : 80x20
      const int r = wid - 1600;
      transpose64(W1, W1t, CDIM, NMLP, isbf, r % 80, r / 80, tid);
    } else {                              // W2 : 20x80
      const int r = wid - 3200;
      transpose64(W2, W2t, NMLP, CDIM, isbf, r % 20, r / 20, tid);
    }
  } else {
    // ---- LN1 ----
    const int row = id - (65 + 4800);
    const int isf32 = !isbf;
    float v[5];
    float s = 0.f, s2 = 0.f;
#pragma unroll
    for (int i = 0; i < 5; ++i) {
      const int c = tid + 256 * i;
      const size_t idx = (size_t)row * CDIM + c;
      v[i] = isf32 ? ((const float*)X)[idx] : (float)((const __bf16*)X)[idx];
      s += v[i];
      s2 += v[i] * v[i];
    }
    const int lane = tid & 63, wv = tid >> 6;
#pragma unroll
    for (int off = 32; off > 0; off >>= 1) {
      s += __shfl_down(s, off);
      s2 += __shfl_down(s2, off);
    }
    __shared__ float red[8];
    if (lane == 0) { red[wv] = s; red[4 + wv] = s2; }
    __syncthreads();
    s = red[0] + red[1] + red[2] + red[3];
    s2 = red[4] + red[5] + red[6] + red[7];
    const float mu = s * (1.f / CDIM);
    const float var = s2 * (1.f / CDIM) - mu * mu;
    const float rstd = rsqrtf(fmaxf(var, 0.f) + 1e-5f);
#pragma unroll
    for (int i = 0; i < 5; ++i) {
      const int c = tid + 256 * i;
      Y[(size_t)row * CDIM + c] =
          (__bf16)((v[i] - mu) * rstd * ld(g1, c) + ld(be1, c));
    }
  }
}

// ---------------- activation transpose: [SEQ][.] -> [N][VTLD] --------------
__global__ __launch_bounds__(256) void transpose_act_kernel(const __bf16* __restrict__ in,
                                                            __bf16* __restrict__ out,
                                                            int istride) {
  __shared__ __bf16 t[32][33];
  const int tx = threadIdx.x, ty = threadIdx.y;
  const int n0 = blockIdx.x * 32, k0 = blockIdx.y * 32;
#pragma unroll
  for (int i = ty; i < 32; i += 8) {
    const int k = k0 + i;
    t[i][tx] = (k < SEQ) ? in[(size_t)k * istride + n0 + tx] : (__bf16)0.f;
  }
  __syncthreads();
#pragma unroll
  for (int i = ty; i < 32; i += 8) {
    const int kk = k0 + tx;
    if (kk < VTLD) out[(size_t)(n0 + i) * VTLD + kk] = t[tx][i];
  }
}

// ---------------- fused: x1 = x + sum(P) + bo ; h2 = LN2(x1) ----------------
__global__ __launch_bounds__(256) void resid_ln_kernel(
    const float* __restrict__ P, const __bf16* __restrict__ bo,
    const void* __restrict__ X, const __bf16* __restrict__ gamma,
    const __bf16* __restrict__ beta, __bf16* __restrict__ X1,
    __bf16* __restrict__ H2, const int* __restrict__ flag) {
  const int isf32 = (flag[0] == 0);
  const int row = blockIdx.x;
  const int MN = SEQ * CDIM;
  float v[5];
  float s = 0.f, s2 = 0.f;
#pragma unroll
  for (int i = 0; i < 5; ++i) {
    const int c = threadIdx.x + 256 * i;
    const size_t idx = (size_t)row * CDIM + c;
    const float xv = isf32 ? ((const float*)X)[idx] : (float)((const __bf16*)X)[idx];
    const float val = P[idx] + P[MN + idx] + (float)bo[c] + xv;
    X1[idx] = (__bf16)val;
    v[i] = val;
    s += val;
    s2 += val * val;
  }
  const int lane = threadIdx.x & 63, wv = threadIdx.x >> 6;
#pragma unroll
  for (int off = 32; off > 0; off >>= 1) {
    s += __shfl_down(s, off);
    s2 += __shfl_down(s2, off);
  }
  __shared__ float red[8];
  if (lane == 0) { red[wv] = s; red[4 + wv] = s2; }
  __syncthreads();
  s = red[0] + red[1] + red[2] + red[3];
  s2 = red[4] + red[5] + red[6] + red[7];
  const float mu = s * (1.f / CDIM);
  const float var = s2 * (1.f / CDIM) - mu * mu;
  const float rstd = rsqrtf(fmaxf(var, 0.f) + 1e-5f);
#pragma unroll
  for (int i = 0; i < 5; ++i) {
    const int c = threadIdx.x + 256 * i;
    H2[(size_t)row * CDIM + c] =
        (__bf16)((v[i] - mu) * rstd * (float)gamma[c] + (float)beta[c]);
  }
}

// ---------------- GEMM 64x128 tile, BK=64 (2 x 32 chunks), 2-barrier -------
// (R5 structure, proven). nsplit>1: fp32 partials. Used for Wo / MLP2.
__global__ __launch_bounds__(256) void gemm64_kernel(
    const __bf16* __restrict__ A, const __bf16* __restrict__ Bt,
    const __bf16* __restrict__ bias, void* __restrict__ Cv,
    int M, int N, int K, int KS, int gelu, int nsplit) {
  __shared__ __bf16 As[2][64 * 32];
  __shared__ __bf16 Bs[2][128 * 32];
  const int bm = blockIdx.x, bn = blockIdx.y, sz = blockIdx.z;
  const int tid = threadIdx.x;
  const int lane = tid & 63, wave = tid >> 6;
  const int l16 = lane & 15, kq = (lane >> 4) << 3;
  const int lrow = lane >> 2, lcol = (lane & 3) << 3;
  const int wn = wave * 32;

  f32x4 acc[4][2];
  const f32x4 zero = {0.f, 0.f, 0.f, 0.f};
#pragma unroll
  for (int i = 0; i < 4; ++i)
#pragma unroll
    for (int j = 0; j < 2; ++j) acc[i][j] = zero;

  const int kbeg = sz * KS;
  int kend = kbeg + KS;
  if (kend > K) kend = K;

  int ga = bm * 64 + wave * 16 + lrow;
  if (ga > M - 1) ga = M - 1;  // clamp: garbage rows never stored
  const __bf16* Ap = A + (size_t)ga * K + lcol;

  for (int k0 = kbeg; k0 < kend; k0 += 64) {
#pragma unroll
    for (int c = 0; c < 2; ++c)
      GLOAD_LDS16(Ap + k0 + c * 32, &As[c][wave * 512]);
#pragma unroll
    for (int c = 0; c < 2; ++c)
#pragma unroll
      for (int t = 0; t < 2; ++t) {
        const int seg = t * 4 + wave;
        const int gb = bn * 128 + seg * 16 + lrow;  // N multiple of 128
        GLOAD_LDS16(Bt + (size_t)gb * K + k0 + c * 32 + lcol, &Bs[c][seg * 512]);
      }
    __syncthreads();
    bf16x8 af[4][2], bfr[2][2];
#pragma unroll
    for (int i = 0; i < 4; ++i)
#pragma unroll
      for (int c = 0; c < 2; ++c)
        af[i][c] = *(const bf16x8*)(&As[c][(i * 16 + l16) * 32 + kq]);
#pragma unroll
    for (int j = 0; j < 2; ++j)
#pragma unroll
      for (int c = 0; c < 2; ++c)
        bfr[j][c] = *(const bf16x8*)(&Bs[c][(wn + j * 16 + l16) * 32 + kq]);
#pragma unroll
    for (int i = 0; i < 4; ++i)
#pragma unroll
      for (int j = 0; j < 2; ++j)
#pragma unroll
        for (int c = 0; c < 2; ++c)
          acc[i][j] = __builtin_amdgcn_mfma_f32_16x16x32_bf16(af[i][c], bfr[j][c],
                                                              acc[i][j], 0, 0, 0);
    __syncthreads();
  }

  const int rq4 = (lane >> 4) * 4;
  if (nsplit > 1) {
    float* P = (float*)Cv + (size_t)sz * M * N;
#pragma unroll
    for (int i = 0; i < 4; ++i)
#pragma unroll
      for (int r = 0; r < 4; ++r) {
        const int grow = bm * 64 + i * 16 + rq4 + r;
        if (grow >= M) continue;
#pragma unroll
        for (int j = 0; j < 2; ++j) {
          const int gcol = bn * 128 + wn + j * 16 + l16;
          P[(size_t)grow * N + gcol] = acc[i][j][r];
        }
      }
  } else {
    __bf16* Cb = (__bf16*)Cv;
#pragma unroll
    for (int i = 0; i < 4; ++i)
#pragma unroll
      for (int r = 0; r < 4; ++r) {
        const int grow = bm * 64 + i * 16 + rq4 + r;
        if (grow >= M) continue;
#pragma unroll
        for (int j = 0; j < 2; ++j) {
          const int gcol = bn * 128 + wn + j * 16 + l16;
          float vv = acc[i][j][r];
          if (bias) vv += (float)bias[gcol];
          if (gelu) vv = 0.5f * vv * (1.f + erff(vv * 0.70710678118654752f));
          Cb[(size_t)grow * N + gcol] = (__bf16)vv;
        }
      }
  }
}

// ---------------- GEMM 128x128, BK=64, counted-vmcnt dbuf (R5 win) ---------
__global__ __launch_bounds__(256, 2) void gemm128c_kernel(
    const __bf16* __restrict__ A, const __bf16* __restrict__ Bt,
    const __bf16* __restrict__ bias, __bf16* __restrict__ C,
    int M, int N, int K, int gelu, int mtiles) {
  __shared__ __bf16 As[2][128 * 64];   // 16 KiB per buf
  __shared__ __bf16 Bs[2][128 * 64];

  // bijective XCD swizzle (m204)
  const int nwg = mtiles * (N >> 7);
  const int qq = nwg >> 3, rr = nwg & 7;
  const int xcd = blockIdx.x & 7, rk = blockIdx.x >> 3;
  const int wg = (xcd < rr ? xcd * (qq + 1) : rr * (qq + 1) + (xcd - rr) * qq) + rk;
  const int bm = wg % mtiles, bn = wg / mtiles;

  const int tid = threadIdx.x;
  const int lane = tid & 63, wave = tid >> 6;
  const int wm = (wave >> 1) * 64, wn = (wave & 1) * 64;   // 2x2 wave grid
  const int l16 = lane & 15, quad = lane >> 4;

  const int rT = tid >> 3, sl = tid & 7;
  const int aoff = ((sl * 16) ^ ((rT & 7) << 4)) >> 1;     // elems
  const __bf16* Ap[4];
  const __bf16* Bp[4];
#pragma unroll
  for (int s = 0; s < 4; ++s) {
    int gm = bm * 128 + s * 32 + rT;
    if (gm > M - 1) gm = M - 1;      // clamp: garbage rows never stored
    Ap[s] = A + (size_t)gm * K + aoff;
    Bp[s] = Bt + (size_t)(bn * 128 + s * 32 + rT) * K + aoff;
  }
  const int ldst = tid * 8;

  const int xsw = (l16 & 7) << 4;
  const int kb0 = ((quad << 4) ^ xsw) >> 1;
  const int kb1 = (((quad << 4) + 64) ^ xsw) >> 1;

  f32x4 acc[4][4];
  const f32x4 zero = {0.f, 0.f, 0.f, 0.f};
#pragma unroll
  for (int i = 0; i < 4; ++i)
#pragma unroll
    for (int j = 0; j < 4; ++j) acc[i][j] = zero;

  const int NT = K >> 6;

#define STAGE128(b, k0)                                       \
  do {                                                        \
    _Pragma("unroll")                                         \
    for (int s = 0; s < 4; ++s) {                             \
      GLOAD_LDS16(Ap[s] + (k0), &As[b][s * 2048 + ldst]);     \
      GLOAD_LDS16(Bp[s] + (k0), &Bs[b][s * 2048 + ldst]);     \
    }                                                         \
  } while (0)

  STAGE128(0, 0);
  for (int t = 0; t < NT; ++t) {
    const int cur = t & 1;
    if (t + 1 < NT) {
      STAGE128(cur ^ 1, (t + 1) * 64);
      asm volatile("s_waitcnt vmcnt(8)" ::: "memory");
    } else {
      asm volatile("s_waitcnt vmcnt(0)" ::: "memory");
    }
    __builtin_amdgcn_s_barrier();
    __builtin_amdgcn_sched_barrier(0);
    bf16x8 af[4][2], bfr[4][2];
#pragma unroll
    for (int i = 0; i < 4; ++i) {
      const int row = (wm + i * 16 + l16) * 64;
      af[i][0] = *(const bf16x8*)(&As[cur][row + kb0]);
      af[i][1] = *(const bf16x8*)(&As[cur][row + kb1]);
    }
#pragma unroll
    for (int j = 0; j < 4; ++j) {
      const int row = (wn + j * 16 + l16) * 64;
      bfr[j][0] = *(const bf16x8*)(&Bs[cur][row + kb0]);
      bfr[j][1] = *(const bf16x8*)(&Bs[cur][row + kb1]);
    }
    __builtin_amdgcn_s_setprio(1);
#pragma unroll
    for (int i = 0; i < 4; ++i)
#pragma unroll
      for (int j = 0; j < 4; ++j)
#pragma unroll
        for (int c = 0; c < 2; ++c)
          acc[i][j] = __builtin_amdgcn_mfma_f32_16x16x32_bf16(af[i][c], bfr[j][c],
                                                              acc[i][j], 0, 0, 0);
    __builtin_amdgcn_s_setprio(0);
    __builtin_amdgcn_s_barrier();
    __builtin_amdgcn_sched_barrier(0);
  }
#undef STAGE128

#pragma unroll
  for (int i = 0; i < 4; ++i)
#pragma unroll
    for (int r = 0; r < 4; ++r) {
      const int grow = bm * 128 + wm + i * 16 + quad * 4 + r;
      if (grow >= M) continue;
#pragma unroll
      for (int j = 0; j < 4; ++j) {
        const int gcol = bn * 128 + wn + j * 16 + l16;
        float vv = acc[i][j][r];
        if (bias) vv += (float)bias[gcol];
        if (gelu) vv = 0.5f * vv * (1.f + erff(vv * 0.70710678118654752f));
        C[(size_t)grow * N + gcol] = (__bf16)vv;
      }
    }
}

// ---------------- final reduce: out = resid + sum(P) + bias ----------------
__global__ __launch_bounds__(256) void reduce_kernel(
    const float* __restrict__ P, const __bf16* __restrict__ bias,
    const __bf16* __restrict__ resid, void* __restrict__ out,
    int MN, int N, const int* __restrict__ flag) {
  const int i = blockIdx.x * 256 + threadIdx.x;
  if (i >= MN) return;
  const float v = P[i] + P[(size_t)MN + i] + (float)bias[i % N] + (float)resid[i];
  if (flag[0]) ((__bf16*)out)[i] = (__bf16)v;
  else         ((float*)out)[i] = v;
}

// ---------------- MFMA flash attention, split-KV (R5 exact) ----------------
__global__ __launch_bounds__(256) void attn_mfma_kernel(
    const __bf16* __restrict__ Q,    // fused base (+0), row stride rs
    const __bf16* __restrict__ Kk,   // fused base + 1280, row stride rs
    const __bf16* __restrict__ Vt,   // [CDIM][VTLD]
    float* __restrict__ Opart,       // [2][SEQ][CDIM]
    float* __restrict__ ml,          // [2][NHEAD][SEQ][2]
    int rs) {
  const int h = blockIdx.y;
  const int q0 = blockIdx.x * 64;
  const int z = blockIdx.z;
  const int tid = threadIdx.x;
  const int wave = tid >> 6, lane = tid & 63;
  const int l16 = lane & 15, quad = lane >> 4;

  __shared__ __bf16 Ks[64 * APAD];
  __shared__ __bf16 Vs[64 * APAD];
  __shared__ __bf16 Ps[4][16 * APAD];

  bf16x8 qf[2];
  {
    int q = q0 + wave * 16 + l16;
    if (q > SEQ - 1) q = SEQ - 1;
    const __bf16* qp = Q + (size_t)q * rs + h * DHEAD + quad * 8;
    qf[0] = *(const bf16x8*)(qp);
    qf[1] = *(const bf16x8*)(qp + 32);
  }

  f32x4 oacc[4];
  const f32x4 zero = {0.f, 0.f, 0.f, 0.f};
#pragma unroll
  for (int jt = 0; jt < 4; ++jt) oacc[jt] = zero;
  float mrow[4], lrow[4];
#pragma unroll
  for (int r = 0; r < 4; ++r) { mrow[r] = -30000.f; lrow[r] = 0.f; }

  const int srow = tid >> 2;
  const int scol = (tid & 3) << 4;

  const __bf16* Kbase = Kk + h * DHEAD;
  const __bf16* Vbase = Vt + (size_t)(h * DHEAD + srow) * VTLD;

  for (int kt = z * 12; kt < z * 12 + 12; ++kt) {
    const int key0 = kt * 64;
    __syncthreads();
    {
      int gk = key0 + srow;
      if (gk > SEQ - 1) gk = SEQ - 1;
      const __bf16* kp = Kbase + (size_t)gk * rs + scol;
      *(bf16x8*)(&Ks[srow * APAD + scol]) = *(const bf16x8*)(kp);
      *(bf16x8*)(&Ks[srow * APAD + scol + 8]) = *(const bf16x8*)(kp + 8);
      const __bf16* vp = Vbase + key0 + scol;
      *(bf16x8*)(&Vs[srow * APAD + scol]) = *(const bf16x8*)(vp);
      *(bf16x8*)(&Vs[srow * APAD + scol + 8]) = *(const bf16x8*)(vp + 8);
    }
    __syncthreads();

    f32x4 s[4];
#pragma unroll
    for (int jt = 0; jt < 4; ++jt) s[jt] = zero;
#pragma unroll
    for (int jt = 0; jt < 4; ++jt)
#pragma unroll
      for (int ks = 0; ks < 2; ++ks) {
        const bf16x8 kf = *(const bf16x8*)(&Ks[(jt * 16 + l16) * APAD + ks * 32 + quad * 8]);
        s[jt] = __builtin_amdgcn_mfma_f32_16x16x32_bf16(qf[ks], kf, s[jt], 0, 0, 0);
      }

#pragma unroll
    for (int jt = 0; jt < 4; ++jt) {
      const int key = key0 + jt * 16 + l16;
#pragma unroll
      for (int r = 0; r < 4; ++r) {
        float sv = s[jt][r] * 0.125f;
        if (key >= SEQ) sv = -30000.f;
        s[jt][r] = sv;
      }
    }

#pragma unroll
    for (int r = 0; r < 4; ++r) {
      float tmax = fmaxf(fmaxf(s[0][r], s[1][r]), fmaxf(s[2][r], s[3][r]));
#pragma unroll
      for (int off = 8; off > 0; off >>= 1) tmax = fmaxf(tmax, __shfl_xor(tmax, off));
      const float mnew = fmaxf(mrow[r], tmax);
      const float alpha = __expf(mrow[r] - mnew);
      mrow[r] = mnew;
      lrow[r] *= alpha;
#pragma unroll
      for (int jt = 0; jt < 4; ++jt) oacc[jt][r] *= alpha;
#pragma unroll
      for (int jt = 0; jt < 4; ++jt) {
        const float p = __expf(s[jt][r] - mnew);
        lrow[r] += p;
        Ps[wave][(quad * 4 + r) * APAD + jt * 16 + l16] = (__bf16)p;
      }
    }

    bf16x8 pf[2];
    pf[0] = *(const bf16x8*)(&Ps[wave][l16 * APAD + quad * 8]);
    pf[1] = *(const bf16x8*)(&Ps[wave][l16 * APAD + 32 + quad * 8]);
#pragma unroll
    for (int jt = 0; jt < 4; ++jt)
#pragma unroll
      for (int ks = 0; ks < 2; ++ks) {
        const bf16x8 vf = *(const bf16x8*)(&Vs[(jt * 16 + l16) * APAD + ks * 32 + quad * 8]);
        oacc[jt] = __builtin_amdgcn_mfma_f32_16x16x32_bf16(pf[ks], vf, oacc[jt], 0, 0, 0);
      }
  }

  float* Oz = Opart + (size_t)z * SEQ * CDIM;
#pragma unroll
  for (int r = 0; r < 4; ++r) {
    float lt = lrow[r];
#pragma unroll
    for (int off = 8; off > 0; off >>= 1) lt += __shfl_xor(lt, off);
    const int q = q0 + wave * 16 + quad * 4 + r;
    if (q < SEQ) {
#pragma unroll
      for (int jt = 0; jt < 4; ++jt)
        Oz[(size_t)q * CDIM + h * DHEAD + jt * 16 + l16] = oacc[jt][r];
      if (l16 == 0) {
        const size_t mi = ((size_t)(z * NHEAD + h) * SEQ + q) * 2;
        ml[mi] = mrow[r];
        ml[mi + 1] = lt;
      }
    }
  }
}

// ---------------- combine the two kv-halves --------------------------------
__global__ __launch_bounds__(256) void attn_combine_kernel(
    const float* __restrict__ Op, const float* __restrict__ ml,
    __bf16* __restrict__ O) {
  const int i = blockIdx.x * 256 + threadIdx.x;
  if (i >= SEQ * CDIM) return;
  const int q = i / CDIM;
  const int h = (i % CDIM) >> 6;
  const size_t m1i = ((size_t)h * SEQ + q) * 2;
  const size_t m2i = ((size_t)(NHEAD + h) * SEQ + q) * 2;
  const float m1 = ml[m1i], l1 = ml[m1i + 1];
  const float m2 = ml[m2i], l2 = ml[m2i + 1];
  const float M = fmaxf(m1, m2);
  const float e1 = __expf(m1 - M), e2 = __expf(m2 - M);
  const float v = (e1 * Op[i] + e2 * Op[(size_t)SEQ * CDIM + i]) /
                  (e1 * l1 + e2 * l2);
  O[i] = (__bf16)v;
}

// ---------------- launch ----------------
extern "C" void kernel_launch(void* const* d_in, const int* in_sizes, int n_in,
                              void* d_out, int out_size, void* d_ws, size_t ws_size,
                              hipStream_t stream) {
  const void* x   = d_in[0];
  const void* Wq  = d_in[1];
  const void* bq  = d_in[2];
  const void* Wk  = d_in[3];
  const void* Wv  = d_in[4];
  const void* bv  = d_in[5];
  const void* Wo  = d_in[6];
  const void* bo  = d_in[7];
  const void* g1  = d_in[8];
  const void* be1 = d_in[9];
  const void* g2  = d_in[10];
  const void* be2 = d_in[11];
  const void* W1  = d_in[12];
  const void* bm1 = d_in[13];
  const void* W2  = d_in[14];
  const void* bm2 = d_in[15];

  char* ws = (char*)d_ws;
  size_t off = 0;
  auto alloc = [&](size_t elems) {
    __bf16* p = (__bf16*)(ws + off);
    off += elems * sizeof(__bf16);
    return p;
  };
  __bf16* Wqkvt = alloc((size_t)QKVN * CDIM);   // Wq^T|Wk^T|Wv^T
  __bf16* Wot   = alloc((size_t)CDIM * CDIM);
  __bf16* W1t   = alloc((size_t)CDIM * NMLP);
  __bf16* W2t   = alloc((size_t)CDIM * NMLP);
  __bf16* qkvb  = alloc((size_t)SEQ * QKVN);    // fused q|k|v; later x1|h2
  __bf16* hb    = alloc((size_t)SEQ * CDIM);    // ln1 out / attn out
  __bf16* mb    = alloc((size_t)SEQ * NMLP);    // mlp hidden; head = Vt
  __bf16* pb    = alloc(20480);                 // packed params
  off = (off + 15) & ~(size_t)15;
  float* pscr = (float*)(ws + off);             // O-partials / split-K partials
  off += (size_t)2 * SEQ * CDIM * sizeof(float);
  float* mlb = (float*)(ws + off);              // attn (m,l): 2 x 20 x 1500 x 2
  off += (size_t)2 * NHEAD * SEQ * 2 * sizeof(float);
  int* flag = (int*)(ws + off);

  __bf16* vtb  = mb;                         // Vt[CDIM][VTLD] (dead before MLP1)
  __bf16* x1b  = qkvb;                       // x1 (qkv dead after attention)
  __bf16* h2b  = qkvb + (size_t)SEQ * CDIM;  // ln2 out

  __bf16* qkvbias = pb + 0;
  __bf16* bo_b  = pb + 3840;
  __bf16* g2_b  = pb + 7680;
  __bf16* be2_b = pb + 8960;
  __bf16* b1_b  = pb + 10240;
  __bf16* b2_b  = pb + 15360;

  // 1. fused prologue: pack + vectorized 64x64 transposes + LN1 (one launch)
  prep_kernel<<<65 + 4800 + SEQ, 256, 0, stream>>>(
      (const unsigned int*)x, x, bq, bv, bo, g1, be1, g2, be2, bm1, bm2,
      Wq, Wk, Wv, Wo, W1, W2, pb, flag, Wqkvt, Wot, W1t, W2t, hb);
  // 2. qkv = h @ Wqkv^T + (bq|0|bv)  [1500][3840], counted-vmcnt 128^2, 360 blk
  gemm128c_kernel<<<360, 256, 0, stream>>>(
      hb, Wqkvt, qkvbias, qkvb, SEQ, QKVN, CDIM, 0, 12);
  // 3. Vt = V^T
  transpose_act_kernel<<<dim3(40, 47), dim3(32, 8), 0, stream>>>(
      qkvb + 2560, vtb, QKVN);
  // 4. attention split-KV partials (R5 exact, z=2)
  attn_mfma_kernel<<<dim3(24, NHEAD, 2), 256, 0, stream>>>(
      qkvb, qkvb + 1280, vtb, pscr, mlb, QKVN);
  // 5. combine -> hb
  attn_combine_kernel<<<7500, 256, 0, stream>>>(pscr, mlb, hb);
  // 6. attn @ Wo (split-K=2, fp32 partials), 480 blocks
  gemm64_kernel<<<dim3(24, 10, 2), 256, 0, stream>>>(
      hb, Wot, nullptr, pscr, SEQ, CDIM, CDIM, 640, 0, 2);
  // 7. fused: x1 = x + partials + bo ; h2 = LN2(x1)
  resid_ln_kernel<<<SEQ, 256, 0, stream>>>(pscr, bo_b, x, g2_b, be2_b,
                                           x1b, h2b, flag);
  // 8. m = gelu(h2 @ W1 + b1)  (counted-vmcnt 128^2, 480 blocks)
  gemm128c_kernel<<<480, 256, 0, stream>>>(
      h2b, W1t, b1_b, mb, SEQ, NMLP, CDIM, 1, 12);
  // 9. m @ W2 (split-K=2), 480 blocks
  gemm64_kernel<<<dim3(24, 10, 2), 256, 0, stream>>>(
      mb, W2t, nullptr, pscr, SEQ, CDIM, NMLP, 2560, 0, 2);
  // 10. out = x1 + partials + b2 (output dtype per flag)
  reduce_kernel<<<7500, 256, 0, stream>>>(pscr, b2_b, x1b, d_out,
                                          SEQ * CDIM, CDIM, flag);
}

// Round 13
// 336.394 us; speedup vs baseline: 1.1075x; 1.0080x over previous
//
#include <hip/hip_runtime.h>
#include <hip/hip_bf16.h>
#include <math.h>

typedef __bf16 bf16x8 __attribute__((ext_vector_type(8)));
typedef float f32x4 __attribute__((ext_vector_type(4)));

#define SEQ 1500
#define CDIM 1280
#define NHEAD 20
#define DHEAD 64
#define NMLP 5120
#define QKVN 3840
#define VTLD 1504   // leading dim of transposed V (47*32)
#define APAD 68     // attention LDS stride

#define GLOAD_LDS16(gp, lp)                                                    \
  __builtin_amdgcn_global_load_lds(                                            \
      (const __attribute__((address_space(1))) unsigned int*)(gp),             \
      (__attribute__((address_space(3))) unsigned int*)(lp), 16, 0, 0)

// ---------------- per-block input-dtype detect (1KB ballot vote on x) ------
__device__ __forceinline__ int detect_bf(const unsigned int* __restrict__ xw,
                                         int tid) {
  __shared__ int shdet[4];
  const unsigned int w = xw[tid & 255];
  const unsigned int e = (w >> 7) & 0xFF;
  const unsigned long long b = __ballot(e >= 100 && e <= 150);
  if ((tid & 63) == 0) shdet[tid >> 6] = (int)__popcll(b);
  __syncthreads();
  return (shdet[0] + shdet[1] + shdet[2] + shdet[3]) >= 160;
}

// ---------------- vectorized 64x64 transpose tile (R12 win) ----------------
__device__ __forceinline__ void transpose64(const void* in, __bf16* out,
                                            int K, int N, int isbf,
                                            int bx, int by, int tid) {
  __shared__ __bf16 t[64 * 66];
  const int n0 = bx * 64, k0 = by * 64;
  if (isbf) {
    const __bf16* s = (const __bf16*)in;
    const int kr = tid >> 3, c = (tid & 7) * 8;    // 32 rows/pass, 8 elems
#pragma unroll
    for (int it = 0; it < 2; ++it) {
      const int k = kr + it * 32;
      const bf16x8 v = *(const bf16x8*)(&s[(size_t)(k0 + k) * N + n0 + c]);
      __bf16* d = &t[k * 66 + c];
#pragma unroll
      for (int j = 0; j < 8; ++j) d[j] = v[j];
    }
  } else {
    const float* s = (const float*)in;
    const int kr = tid >> 4, c = (tid & 15) * 4;   // 16 rows/pass, 4 elems
#pragma unroll
    for (int it = 0; it < 4; ++it) {
      const int k = kr + it * 16;
      const float4 v = *(const float4*)(&s[(size_t)(k0 + k) * N + n0 + c]);
      __bf16* d = &t[k * 66 + c];
      d[0] = (__bf16)v.x; d[1] = (__bf16)v.y;
      d[2] = (__bf16)v.z; d[3] = (__bf16)v.w;
    }
  }
  __syncthreads();
  const int nr = tid >> 3, kc = (tid & 7) * 8;
#pragma unroll
  for (int it = 0; it < 2; ++it) {
    const int n = nr + it * 32;
    bf16x8 v;
#pragma unroll
    for (int j = 0; j < 8; ++j) v[j] = t[(kc + j) * 66 + n];
    *(bf16x8*)(&out[(size_t)(n0 + n) * K + k0 + kc]) = v;
  }
}

// ---------------- fused prologue: pack + all weight transposes + LN1 -------
// grid: 65 pack | 4800 transpose tiles | 1500 LN1 = 6365 blocks
__global__ __launch_bounds__(256) void prep_kernel(
    const unsigned int* __restrict__ xw, const void* __restrict__ X,
    const void* bq, const void* bv, const void* bo,
    const void* g1, const void* be1, const void* g2, const void* be2,
    const void* b1, const void* b2,
    const void* Wq, const void* Wk, const void* Wv, const void* Wo,
    const void* W1, const void* W2,
    __bf16* __restrict__ pb, int* __restrict__ flag,
    __bf16* __restrict__ Wqkvt, __bf16* __restrict__ Wot,
    __bf16* __restrict__ W1t, __bf16* __restrict__ W2t,
    __bf16* __restrict__ Y) {
  const int tid = threadIdx.x;
  const int isbf = detect_bf(xw, tid);
  auto ld = [&](const void* p, int j) -> float {
    return isbf ? (float)((const __bf16*)p)[j] : ((const float*)p)[j];
  };
  const int id = blockIdx.x;

  if (id < 65) {
    // ---- pack params ----
    if (id == 0 && tid == 0) flag[0] = isbf;
    const int i = id * 256 + tid;
    if (i >= 16640) return;
    float v;
    if (i < 3840) {
      if (i < 1280) v = ld(bq, i);
      else if (i < 2560) v = 0.f;
      else v = ld(bv, i - 2560);
    } else if (i < 5120) v = ld(bo, i - 3840);
    else if (i < 6400) v = ld(g1, i - 5120);
    else if (i < 7680) v = ld(be1, i - 6400);
    else if (i < 8960) v = ld(g2, i - 7680);
    else if (i < 10240) v = ld(be2, i - 8960);
    else if (i < 15360) v = ld(b1, i - 10240);
    else v = ld(b2, i - 15360);
    pb[i] = (__bf16)v;
  } else if (id < 65 + 4800) {
    // ---- weight transposes (64x64 tiles) ----
    const int wid = id - 65;
    if (wid < 1600) {                     // Wq|Wk|Wv|Wo : 4 x (20x20)
      const int w = wid / 400, r = wid % 400;
      const void* in = (w == 0) ? Wq : (w == 1) ? Wk : (w == 2) ? Wv : Wo;
      __bf16* out = (w < 3) ? (Wqkvt + (size_t)w * CDIM * CDIM) : Wot;
      transpose64(in, out, CDIM, CDIM, isbf, r % 20, r / 20, tid);
    } else if (wid < 3200) {              // W1 : 80x20
      const int r = wid - 1600;
      transpose64(W1, W1t, CDIM, NMLP, isbf, r % 80, r / 80, tid);
    } else {                              // W2 : 20x80
      const int r = wid - 3200;
      transpose64(W2, W2t, NMLP, CDIM, isbf, r % 20, r / 20, tid);
    }
  } else {
    // ---- LN1 ----
    const int row = id - (65 + 4800);
    const int isf32 = !isbf;
    float v[5];
    float s = 0.f, s2 = 0.f;
#pragma unroll
    for (int i = 0; i < 5; ++i) {
      const int c = tid + 256 * i;
      const size_t idx = (size_t)row * CDIM + c;
      v[i] = isf32 ? ((const float*)X)[idx] : (float)((const __bf16*)X)[idx];
      s += v[i];
      s2 += v[i] * v[i];
    }
    const int lane = tid & 63, wv = tid >> 6;
#pragma unroll
    for (int off = 32; off > 0; off >>= 1) {
      s += __shfl_down(s, off);
      s2 += __shfl_down(s2, off);
    }
    __shared__ float red[8];
    if (lane == 0) { red[wv] = s; red[4 + wv] = s2; }
    __syncthreads();
    s = red[0] + red[1] + red[2] + red[3];
    s2 = red[4] + red[5] + red[6] + red[7];
    const float mu = s * (1.f / CDIM);
    const float var = s2 * (1.f / CDIM) - mu * mu;
    const float rstd = rsqrtf(fmaxf(var, 0.f) + 1e-5f);
#pragma unroll
    for (int i = 0; i < 5; ++i) {
      const int c = tid + 256 * i;
      Y[(size_t)row * CDIM + c] =
          (__bf16)((v[i] - mu) * rstd * ld(g1, c) + ld(be1, c));
    }
  }
}

// -------- activation transpose, vectorized (R13): [SEQ][.] -> [N][VTLD] ----
// 64x64 bf16x8 tiles; row guard at SEQ (zeros), write guard at VTLD (the
// last col-tile keeps only kc<=24, matching the original 1504-col coverage).
__global__ __launch_bounds__(256) void transpose_act64_kernel(
    const __bf16* __restrict__ in, __bf16* __restrict__ out, int istride) {
  __shared__ __bf16 t[64 * 66];
  const int tid = threadIdx.x;
  const int n0 = blockIdx.x * 64;      // V col (CDIM)
  const int k0 = blockIdx.y * 64;      // seq row
  const int kr = tid >> 3, c = (tid & 7) * 8;
#pragma unroll
  for (int it = 0; it < 2; ++it) {
    const int k = kr + it * 32;
    bf16x8 v;
    if (k0 + k < SEQ) {
      v = *(const bf16x8*)(&in[(size_t)(k0 + k) * istride + n0 + c]);
    } else {
#pragma unroll
      for (int j = 0; j < 8; ++j) v[j] = (__bf16)0.f;
    }
    __bf16* d = &t[k * 66 + c];
#pragma unroll
    for (int j = 0; j < 8; ++j) d[j] = v[j];
  }
  __syncthreads();
  const int nr = tid >> 3, kc = (tid & 7) * 8;
#pragma unroll
  for (int it = 0; it < 2; ++it) {
    const int n = nr + it * 32;
    const int kk = k0 + kc;
    if (kk + 8 <= VTLD) {
      bf16x8 v;
#pragma unroll
      for (int j = 0; j < 8; ++j) v[j] = t[(kc + j) * 66 + n];
      *(bf16x8*)(&out[(size_t)(n0 + n) * VTLD + kk]) = v;
    }
  }
}

// ---------------- fused: x1 = x + sum(P[0..1]) + bo ; h2 = LN2(x1) ---------
__global__ __launch_bounds__(256) void resid_ln_kernel(
    const float* __restrict__ P, const __bf16* __restrict__ bo,
    const void* __restrict__ X, const __bf16* __restrict__ gamma,
    const __bf16* __restrict__ beta, __bf16* __restrict__ X1,
    __bf16* __restrict__ H2, const int* __restrict__ flag) {
  const int isf32 = (flag[0] == 0);
  const int row = blockIdx.x;
  const int MN = SEQ * CDIM;
  float v[5];
  float s = 0.f, s2 = 0.f;
#pragma unroll
  for (int i = 0; i < 5; ++i) {
    const int c = threadIdx.x + 256 * i;
    const size_t idx = (size_t)row * CDIM + c;
    const float xv = isf32 ? ((const float*)X)[idx] : (float)((const __bf16*)X)[idx];
    const float val = P[idx] + P[MN + idx] + (float)bo[c] + xv;
    X1[idx] = (__bf16)val;
    v[i] = val;
    s += val;
    s2 += val * val;
  }
  const int lane = threadIdx.x & 63, wv = threadIdx.x >> 6;
#pragma unroll
  for (int off = 32; off > 0; off >>= 1) {
    s += __shfl_down(s, off);
    s2 += __shfl_down(s2, off);
  }
  __shared__ float red[8];
  if (lane == 0) { red[wv] = s; red[4 + wv] = s2; }
  __syncthreads();
  s = red[0] + red[1] + red[2] + red[3];
  s2 = red[4] + red[5] + red[6] + red[7];
  const float mu = s * (1.f / CDIM);
  const float var = s2 * (1.f / CDIM) - mu * mu;
  const float rstd = rsqrtf(fmaxf(var, 0.f) + 1e-5f);
#pragma unroll
  for (int i = 0; i < 5; ++i) {
    const int c = threadIdx.x + 256 * i;
    H2[(size_t)row * CDIM + c] =
        (__bf16)((v[i] - mu) * rstd * (float)gamma[c] + (float)beta[c]);
  }
}

// ---------------- GEMM 64x128 tile, BK=64 (2 x 32 chunks), 2-barrier -------
// (R5 structure, proven). nsplit>1: fp32 partials. Used for Wo / MLP2.
__global__ __launch_bounds__(256) void gemm64_kernel(
    const __bf16* __restrict__ A, const __bf16* __restrict__ Bt,
    const __bf16* __restrict__ bias, void* __restrict__ Cv,
    int M, int N, int K, int KS, int gelu, int nsplit) {
  __shared__ __bf16 As[2][64 * 32];
  __shared__ __bf16 Bs[2][128 * 32];
  const int bm = blockIdx.x, bn = blockIdx.y, sz = blockIdx.z;
  const int tid = threadIdx.x;
  const int lane = tid & 63, wave = tid >> 6;
  const int l16 = lane & 15, kq = (lane >> 4) << 3;
  const int lrow = lane >> 2, lcol = (lane & 3) << 3;
  const int wn = wave * 32;

  f32x4 acc[4][2];
  const f32x4 zero = {0.f, 0.f, 0.f, 0.f};
#pragma unroll
  for (int i = 0; i < 4; ++i)
#pragma unroll
    for (int j = 0; j < 2; ++j) acc[i][j] = zero;

  const int kbeg = sz * KS;
  int kend = kbeg + KS;
  if (kend > K) kend = K;

  int ga = bm * 64 + wave * 16 + lrow;
  if (ga > M - 1) ga = M - 1;  // clamp: garbage rows never stored
  const __bf16* Ap = A + (size_t)ga * K + lcol;

  for (int k0 = kbeg; k0 < kend; k0 += 64) {
#pragma unroll
    for (int c = 0; c < 2; ++c)
      GLOAD_LDS16(Ap + k0 + c * 32, &As[c][wave * 512]);
#pragma unroll
    for (int c = 0; c < 2; ++c)
#pragma unroll
      for (int t = 0; t < 2; ++t) {
        const int seg = t * 4 + wave;
        const int gb = bn * 128 + seg * 16 + lrow;  // N multiple of 128
        GLOAD_LDS16(Bt + (size_t)gb * K + k0 + c * 32 + lcol, &Bs[c][seg * 512]);
      }
    __syncthreads();
    bf16x8 af[4][2], bfr[2][2];
#pragma unroll
    for (int i = 0; i < 4; ++i)
#pragma unroll
      for (int c = 0; c < 2; ++c)
        af[i][c] = *(const bf16x8*)(&As[c][(i * 16 + l16) * 32 + kq]);
#pragma unroll
    for (int j = 0; j < 2; ++j)
#pragma unroll
      for (int c = 0; c < 2; ++c)
        bfr[j][c] = *(const bf16x8*)(&Bs[c][(wn + j * 16 + l16) * 32 + kq]);
#pragma unroll
    for (int i = 0; i < 4; ++i)
#pragma unroll
      for (int j = 0; j < 2; ++j)
#pragma unroll
        for (int c = 0; c < 2; ++c)
          acc[i][j] = __builtin_amdgcn_mfma_f32_16x16x32_bf16(af[i][c], bfr[j][c],
                                                              acc[i][j], 0, 0, 0);
    __syncthreads();
  }

  const int rq4 = (lane >> 4) * 4;
  if (nsplit > 1) {
    float* P = (float*)Cv + (size_t)sz * M * N;
#pragma unroll
    for (int i = 0; i < 4; ++i)
#pragma unroll
      for (int r = 0; r < 4; ++r) {
        const int grow = bm * 64 + i * 16 + rq4 + r;
        if (grow >= M) continue;
#pragma unroll
        for (int j = 0; j < 2; ++j) {
          const int gcol = bn * 128 + wn + j * 16 + l16;
          P[(size_t)grow * N + gcol] = acc[i][j][r];
        }
      }
  } else {
    __bf16* Cb = (__bf16*)Cv;
#pragma unroll
    for (int i = 0; i < 4; ++i)
#pragma unroll
      for (int r = 0; r < 4; ++r) {
        const int grow = bm * 64 + i * 16 + rq4 + r;
        if (grow >= M) continue;
#pragma unroll
        for (int j = 0; j < 2; ++j) {
          const int gcol = bn * 128 + wn + j * 16 + l16;
          float vv = acc[i][j][r];
          if (bias) vv += (float)bias[gcol];
          if (gelu) vv = 0.5f * vv * (1.f + erff(vv * 0.70710678118654752f));
          Cb[(size_t)grow * N + gcol] = (__bf16)vv;
        }
      }
  }
}

// ---------------- GEMM 128x128, BK=64, counted-vmcnt dbuf (R5 win) ---------
__global__ __launch_bounds__(256, 2) void gemm128c_kernel(
    const __bf16* __restrict__ A, const __bf16* __restrict__ Bt,
    const __bf16* __restrict__ bias, __bf16* __restrict__ C,
    int M, int N, int K, int gelu, int mtiles) {
  __shared__ __bf16 As[2][128 * 64];   // 16 KiB per buf
  __shared__ __bf16 Bs[2][128 * 64];

  // bijective XCD swizzle (m204)
  const int nwg = mtiles * (N >> 7);
  const int qq = nwg >> 3, rr = nwg & 7;
  const int xcd = blockIdx.x & 7, rk = blockIdx.x >> 3;
  const int wg = (xcd < rr ? xcd * (qq + 1) : rr * (qq + 1) + (xcd - rr) * qq) + rk;
  const int bm = wg % mtiles, bn = wg / mtiles;

  const int tid = threadIdx.x;
  const int lane = tid & 63, wave = tid >> 6;
  const int wm = (wave >> 1) * 64, wn = (wave & 1) * 64;   // 2x2 wave grid
  const int l16 = lane & 15, quad = lane >> 4;

  const int rT = tid >> 3, sl = tid & 7;
  const int aoff = ((sl * 16) ^ ((rT & 7) << 4)) >> 1;     // elems
  const __bf16* Ap[4];
  const __bf16* Bp[4];
#pragma unroll
  for (int s = 0; s < 4; ++s) {
    int gm = bm * 128 + s * 32 + rT;
    if (gm > M - 1) gm = M - 1;      // clamp: garbage rows never stored
    Ap[s] = A + (size_t)gm * K + aoff;
    Bp[s] = Bt + (size_t)(bn * 128 + s * 32 + rT) * K + aoff;
  }
  const int ldst = tid * 8;

  const int xsw = (l16 & 7) << 4;
  const int kb0 = ((quad << 4) ^ xsw) >> 1;
  const int kb1 = (((quad << 4) + 64) ^ xsw) >> 1;

  f32x4 acc[4][4];
  const f32x4 zero = {0.f, 0.f, 0.f, 0.f};
#pragma unroll
  for (int i = 0; i < 4; ++i)
#pragma unroll
    for (int j = 0; j < 4; ++j) acc[i][j] = zero;

  const int NT = K >> 6;

#define STAGE128(b, k0)                                       \
  do {                                                        \
    _Pragma("unroll")                                         \
    for (int s = 0; s < 4; ++s) {                             \
      GLOAD_LDS16(Ap[s] + (k0), &As[b][s * 2048 + ldst]);     \
      GLOAD_LDS16(Bp[s] + (k0), &Bs[b][s * 2048 + ldst]);     \
    }                                                         \
  } while (0)

  STAGE128(0, 0);
  for (int t = 0; t < NT; ++t) {
    const int cur = t & 1;
    if (t + 1 < NT) {
      STAGE128(cur ^ 1, (t + 1) * 64);
      asm volatile("s_waitcnt vmcnt(8)" ::: "memory");
    } else {
      asm volatile("s_waitcnt vmcnt(0)" ::: "memory");
    }
    __builtin_amdgcn_s_barrier();
    __builtin_amdgcn_sched_barrier(0);
    bf16x8 af[4][2], bfr[4][2];
#pragma unroll
    for (int i = 0; i < 4; ++i) {
      const int row = (wm + i * 16 + l16) * 64;
      af[i][0] = *(const bf16x8*)(&As[cur][row + kb0]);
      af[i][1] = *(const bf16x8*)(&As[cur][row + kb1]);
    }
#pragma unroll
    for (int j = 0; j < 4; ++j) {
      const int row = (wn + j * 16 + l16) * 64;
      bfr[j][0] = *(const bf16x8*)(&Bs[cur][row + kb0]);
      bfr[j][1] = *(const bf16x8*)(&Bs[cur][row + kb1]);
    }
    __builtin_amdgcn_s_setprio(1);
#pragma unroll
    for (int i = 0; i < 4; ++i)
#pragma unroll
      for (int j = 0; j < 4; ++j)
#pragma unroll
        for (int c = 0; c < 2; ++c)
          acc[i][j] = __builtin_amdgcn_mfma_f32_16x16x32_bf16(af[i][c], bfr[j][c],
                                                              acc[i][j], 0, 0, 0);
    __builtin_amdgcn_s_setprio(0);
    __builtin_amdgcn_s_barrier();
    __builtin_amdgcn_sched_barrier(0);
  }
#undef STAGE128

#pragma unroll
  for (int i = 0; i < 4; ++i)
#pragma unroll
    for (int r = 0; r < 4; ++r) {
      const int grow = bm * 128 + wm + i * 16 + quad * 4 + r;
      if (grow >= M) continue;
#pragma unroll
      for (int j = 0; j < 4; ++j) {
        const int gcol = bn * 128 + wn + j * 16 + l16;
        float vv = acc[i][j][r];
        if (bias) vv += (float)bias[gcol];
        if (gelu) vv = 0.5f * vv * (1.f + erff(vv * 0.70710678118654752f));
        C[(size_t)grow * N + gcol] = (__bf16)vv;
      }
    }
}

// ---------------- final reduce: out = resid + sum(P[0..3]) + bias ----------
__global__ __launch_bounds__(256) void reduce_kernel(
    const float* __restrict__ P, const __bf16* __restrict__ bias,
    const __bf16* __restrict__ resid, void* __restrict__ out,
    int MN, int N, const int* __restrict__ flag) {
  const int i = blockIdx.x * 256 + threadIdx.x;
  if (i >= MN) return;
  const float v = P[i] + P[(size_t)MN + i] + P[(size_t)2 * MN + i] +
                  P[(size_t)3 * MN + i] + (float)bias[i % N] + (float)resid[i];
  if (flag[0]) ((__bf16*)out)[i] = (__bf16)v;
  else         ((float*)out)[i] = v;
}

// ---------------- MFMA flash attention, split-KV (R5 exact) ----------------
__global__ __launch_bounds__(256) void attn_mfma_kernel(
    const __bf16* __restrict__ Q,    // fused base (+0), row stride rs
    const __bf16* __restrict__ Kk,   // fused base + 1280, row stride rs
    const __bf16* __restrict__ Vt,   // [CDIM][VTLD]
    float* __restrict__ Opart,       // [2][SEQ][CDIM]
    float* __restrict__ ml,          // [2][NHEAD][SEQ][2]
    int rs) {
  const int h = blockIdx.y;
  const int q0 = blockIdx.x * 64;
  const int z = blockIdx.z;
  const int tid = threadIdx.x;
  const int wave = tid >> 6, lane = tid & 63;
  const int l16 = lane & 15, quad = lane >> 4;

  __shared__ __bf16 Ks[64 * APAD];
  __shared__ __bf16 Vs[64 * APAD];
  __shared__ __bf16 Ps[4][16 * APAD];

  bf16x8 qf[2];
  {
    int q = q0 + wave * 16 + l16;
    if (q > SEQ - 1) q = SEQ - 1;
    const __bf16* qp = Q + (size_t)q * rs + h * DHEAD + quad * 8;
    qf[0] = *(const bf16x8*)(qp);
    qf[1] = *(const bf16x8*)(qp + 32);
  }

  f32x4 oacc[4];
  const f32x4 zero = {0.f, 0.f, 0.f, 0.f};
#pragma unroll
  for (int jt = 0; jt < 4; ++jt) oacc[jt] = zero;
  float mrow[4], lrow[4];
#pragma unroll
  for (int r = 0; r < 4; ++r) { mrow[r] = -30000.f; lrow[r] = 0.f; }

  const int srow = tid >> 2;
  const int scol = (tid & 3) << 4;

  const __bf16* Kbase = Kk + h * DHEAD;
  const __bf16* Vbase = Vt + (size_t)(h * DHEAD + srow) * VTLD;

  for (int kt = z * 12; kt < z * 12 + 12; ++kt) {
    const int key0 = kt * 64;
    __syncthreads();
    {
      int gk = key0 + srow;
      if (gk > SEQ - 1) gk = SEQ - 1;
      const __bf16* kp = Kbase + (size_t)gk * rs + scol;
      *(bf16x8*)(&Ks[srow * APAD + scol]) = *(const bf16x8*)(kp);
      *(bf16x8*)(&Ks[srow * APAD + scol + 8]) = *(const bf16x8*)(kp + 8);
      const __bf16* vp = Vbase + key0 + scol;
      *(bf16x8*)(&Vs[srow * APAD + scol]) = *(const bf16x8*)(vp);
      *(bf16x8*)(&Vs[srow * APAD + scol + 8]) = *(const bf16x8*)(vp + 8);
    }
    __syncthreads();

    f32x4 s[4];
#pragma unroll
    for (int jt = 0; jt < 4; ++jt) s[jt] = zero;
#pragma unroll
    for (int jt = 0; jt < 4; ++jt)
#pragma unroll
      for (int ks = 0; ks < 2; ++ks) {
        const bf16x8 kf = *(const bf16x8*)(&Ks[(jt * 16 + l16) * APAD + ks * 32 + quad * 8]);
        s[jt] = __builtin_amdgcn_mfma_f32_16x16x32_bf16(qf[ks], kf, s[jt], 0, 0, 0);
      }

#pragma unroll
    for (int jt = 0; jt < 4; ++jt) {
      const int key = key0 + jt * 16 + l16;
#pragma unroll
      for (int r = 0; r < 4; ++r) {
        float sv = s[jt][r] * 0.125f;
        if (key >= SEQ) sv = -30000.f;
        s[jt][r] = sv;
      }
    }

#pragma unroll
    for (int r = 0; r < 4; ++r) {
      float tmax = fmaxf(fmaxf(s[0][r], s[1][r]), fmaxf(s[2][r], s[3][r]));
#pragma unroll
      for (int off = 8; off > 0; off >>= 1) tmax = fmaxf(tmax, __shfl_xor(tmax, off));
      const float mnew = fmaxf(mrow[r], tmax);
      const float alpha = __expf(mrow[r] - mnew);
      mrow[r] = mnew;
      lrow[r] *= alpha;
#pragma unroll
      for (int jt = 0; jt < 4; ++jt) oacc[jt][r] *= alpha;
#pragma unroll
      for (int jt = 0; jt < 4; ++jt) {
        const float p = __expf(s[jt][r] - mnew);
        lrow[r] += p;
        Ps[wave][(quad * 4 + r) * APAD + jt * 16 + l16] = (__bf16)p;
      }
    }

    bf16x8 pf[2];
    pf[0] = *(const bf16x8*)(&Ps[wave][l16 * APAD + quad * 8]);
    pf[1] = *(const bf16x8*)(&Ps[wave][l16 * APAD + 32 + quad * 8]);
#pragma unroll
    for (int jt = 0; jt < 4; ++jt)
#pragma unroll
      for (int ks = 0; ks < 2; ++ks) {
        const bf16x8 vf = *(const bf16x8*)(&Vs[(jt * 16 + l16) * APAD + ks * 32 + quad * 8]);
        oacc[jt] = __builtin_amdgcn_mfma_f32_16x16x32_bf16(pf[ks], vf, oacc[jt], 0, 0, 0);
      }
  }

  float* Oz = Opart + (size_t)z * SEQ * CDIM;
#pragma unroll
  for (int r = 0; r < 4; ++r) {
    float lt = lrow[r];
#pragma unroll
    for (int off = 8; off > 0; off >>= 1) lt += __shfl_xor(lt, off);
    const int q = q0 + wave * 16 + quad * 4 + r;
    if (q < SEQ) {
#pragma unroll
      for (int jt = 0; jt < 4; ++jt)
        Oz[(size_t)q * CDIM + h * DHEAD + jt * 16 + l16] = oacc[jt][r];
      if (l16 == 0) {
        const size_t mi = ((size_t)(z * NHEAD + h) * SEQ + q) * 2;
        ml[mi] = mrow[r];
        ml[mi + 1] = lt;
      }
    }
  }
}

// ---------------- combine the two kv-halves --------------------------------
__global__ __launch_bounds__(256) void attn_combine_kernel(
    const float* __restrict__ Op, const float* __restrict__ ml,
    __bf16* __restrict__ O) {
  const int i = blockIdx.x * 256 + threadIdx.x;
  if (i >= SEQ * CDIM) return;
  const int q = i / CDIM;
  const int h = (i % CDIM) >> 6;
  const size_t m1i = ((size_t)h * SEQ + q) * 2;
  const size_t m2i = ((size_t)(NHEAD + h) * SEQ + q) * 2;
  const float m1 = ml[m1i], l1 = ml[m1i + 1];
  const float m2 = ml[m2i], l2 = ml[m2i + 1];
  const float M = fmaxf(m1, m2);
  const float e1 = __expf(m1 - M), e2 = __expf(m2 - M);
  const float v = (e1 * Op[i] + e2 * Op[(size_t)SEQ * CDIM + i]) /
                  (e1 * l1 + e2 * l2);
  O[i] = (__bf16)v;
}

// ---------------- launch ----------------
extern "C" void kernel_launch(void* const* d_in, const int* in_sizes, int n_in,
                              void* d_out, int out_size, void* d_ws, size_t ws_size,
                              hipStream_t stream) {
  const void* x   = d_in[0];
  const void* Wq  = d_in[1];
  const void* bq  = d_in[2];
  const void* Wk  = d_in[3];
  const void* Wv  = d_in[4];
  const void* bv  = d_in[5];
  const void* Wo  = d_in[6];
  const void* bo  = d_in[7];
  const void* g1  = d_in[8];
  const void* be1 = d_in[9];
  const void* g2  = d_in[10];
  const void* be2 = d_in[11];
  const void* W1  = d_in[12];
  const void* bm1 = d_in[13];
  const void* W2  = d_in[14];
  const void* bm2 = d_in[15];

  char* ws = (char*)d_ws;
  size_t off = 0;
  auto alloc = [&](size_t elems) {
    __bf16* p = (__bf16*)(ws + off);
    off += elems * sizeof(__bf16);
    return p;
  };
  __bf16* Wqkvt = alloc((size_t)QKVN * CDIM);   // Wq^T|Wk^T|Wv^T
  __bf16* Wot   = alloc((size_t)CDIM * CDIM);
  __bf16* W1t   = alloc((size_t)CDIM * NMLP);
  __bf16* W2t   = alloc((size_t)CDIM * NMLP);
  __bf16* qkvb  = alloc((size_t)SEQ * QKVN);    // fused q|k|v; later x1|h2
  __bf16* hb    = alloc((size_t)SEQ * CDIM);    // ln1 out / attn out
  __bf16* mb    = alloc((size_t)SEQ * NMLP);    // mlp hidden; head = Vt
  __bf16* pb    = alloc(20480);                 // packed params
  off = (off + 15) & ~(size_t)15;
  float* pscr = (float*)(ws + off);             // O-partials / split-K partials
  off += (size_t)4 * SEQ * CDIM * sizeof(float);   // 4 slots (MLP2 split-4)
  float* mlb = (float*)(ws + off);              // attn (m,l): 2 x 20 x 1500 x 2
  off += (size_t)2 * NHEAD * SEQ * 2 * sizeof(float);
  int* flag = (int*)(ws + off);

  __bf16* vtb  = mb;                         // Vt[CDIM][VTLD] (dead before MLP1)
  __bf16* x1b  = qkvb;                       // x1 (qkv dead after attention)
  __bf16* h2b  = qkvb + (size_t)SEQ * CDIM;  // ln2 out

  __bf16* qkvbias = pb + 0;
  __bf16* bo_b  = pb + 3840;
  __bf16* g2_b  = pb + 7680;
  __bf16* be2_b = pb + 8960;
  __bf16* b1_b  = pb + 10240;
  __bf16* b2_b  = pb + 15360;

  // 1. fused prologue: pack + vectorized 64x64 transposes + LN1 (one launch)
  prep_kernel<<<65 + 4800 + SEQ, 256, 0, stream>>>(
      (const unsigned int*)x, x, bq, bv, bo, g1, be1, g2, be2, bm1, bm2,
      Wq, Wk, Wv, Wo, W1, W2, pb, flag, Wqkvt, Wot, W1t, W2t, hb);
  // 2. qkv = h @ Wqkv^T + (bq|0|bv)  [1500][3840], counted-vmcnt 128^2, 360 blk
  gemm128c_kernel<<<360, 256, 0, stream>>>(
      hb, Wqkvt, qkvbias, qkvb, SEQ, QKVN, CDIM, 0, 12);
  // 3. Vt = V^T (vectorized 64x64, R13)
  transpose_act64_kernel<<<dim3(20, 24), 256, 0, stream>>>(
      qkvb + 2560, vtb, QKVN);
  // 4. attention split-KV partials (R5 exact, z=2)
  attn_mfma_kernel<<<dim3(24, NHEAD, 2), 256, 0, stream>>>(
      qkvb, qkvb + 1280, vtb, pscr, mlb, QKVN);
  // 5. combine -> hb
  attn_combine_kernel<<<7500, 256, 0, stream>>>(pscr, mlb, hb);
  // 6. attn @ Wo (split-K=2, fp32 partials), 480 blocks
  gemm64_kernel<<<dim3(24, 10, 2), 256, 0, stream>>>(
      hb, Wot, nullptr, pscr, SEQ, CDIM, CDIM, 640, 0, 2);
  // 7. fused: x1 = x + partials + bo ; h2 = LN2(x1)
  resid_ln_kernel<<<SEQ, 256, 0, stream>>>(pscr, bo_b, x, g2_b, be2_b,
                                           x1b, h2b, flag);
  // 8. m = gelu(h2 @ W1 + b1)  (counted-vmcnt 128^2, 480 blocks)
  gemm128c_kernel<<<480, 256, 0, stream>>>(
      h2b, W1t, b1_b, mb, SEQ, NMLP, CDIM, 1, 12);
  // 9. m @ W2 (split-K=4, 960 blocks: halves per-block serial K-length)
  gemm64_kernel<<<dim3(24, 10, 4), 256, 0, stream>>>(
      mb, W2t, nullptr, pscr, SEQ, CDIM, NMLP, 1280, 0, 4);
  // 10. out = x1 + sum of 4 partials + b2 (output dtype per flag)
  reduce_kernel<<<7500, 256, 0, stream>>>(pscr, b2_b, x1b, d_out,
                                          SEQ * CDIM, CDIM, flag);
}